// Round 5
// baseline (1431.749 us; speedup 1.0000x reference)
//
#include <hip/hip_runtime.h>

typedef __attribute__((ext_vector_type(8))) short bfrag_t;   // 8 x bf16 (4 VGPRs)
typedef __attribute__((ext_vector_type(4))) float f4_t;
typedef __attribute__((ext_vector_type(2))) float f2_t;

#define LOG_2PI   1.8378770664093453f
#define TWO_LOG2  1.3862943611198906f
#define T_TILES   8            // 16-point tiles per wave
#define BLOCK     256          // 4 waves
#define PTS_BLK   512          // 4 waves * 8 tiles * 16 pts

struct SM {
  uint4    afr[2][8][64];      // 16KB [mlp][frag=q*4+n][lane] pre-swizzled bf16 W2 A-frags (single buf)
  float2   z01[PTS_BLK];       // 4KB  per-point (z0, z1)
  float    ld[PTS_BLK];        // 2KB  per-point log-det accumulator
  float    c1[6][2][64];       // 3KB  w1[j][jm]
  float    b1[6][2][64];       // 3KB  b1[j]
  float    b2f[6][2][64];      // 3KB  b2[j] fp32 (MFMA C-init, fed by ds_read_b128)
  float    w3f[6][2][64];      // 3KB  w3[jo][j] fp32
  float    wsum[4];
};                             // total ~34.8KB -> 4 blocks/CU

__device__ __forceinline__ unsigned pkbf(float lo, float hi) {
  unsigned r;
  asm("v_cvt_pk_bf16_f32 %0, %1, %2" : "=v"(r) : "v"(lo), "v"(hi));
  return r;
}
__device__ __forceinline__ f2_t pk_fma(f2_t a, f2_t b, f2_t c) {
  f2_t d;
  asm("v_pk_fma_f32 %0, %1, %2, %3" : "=v"(d) : "v"(a), "v"(b), "v"(c));
  return d;
}
// leaky-relu on 2 lanes: packed mul + 2 scalar max (no v_pk_max_f32 on gfx950)
__device__ __forceinline__ f2_t pk_leaky(f2_t h, f2_t k01) {
  f2_t t, r;
  asm("v_pk_mul_f32 %0, %1, %2" : "=v"(t) : "v"(h), "v"(k01));
  r.x = fmaxf(h.x, t.x);
  r.y = fmaxf(h.y, t.y);
  return r;
}

// Stage one layer's W2 (both MLPs) into LDS as MFMA A-fragments (bf16).
// A-frag layout for mfma_f32_16x16x32_bf16: lane l holds A[16n + (l&15)][32q + 8*(l>>4) + e], e=0..7
__device__ __forceinline__ void stage_layer(SM* sm, const float* sW2, const float* tW2,
                                            int layer, int tid) {
  #pragma unroll
  for (int it = 0; it < 4; ++it) {
    int idx = tid + it * BLOCK;          // 0..1023
    int l = idx & 63, f = (idx >> 6) & 7, m = (idx >> 9) & 1;
    int n = f & 3, q = f >> 2;
    int row = 16 * n + (l & 15), kb = 32 * q + 8 * (l >> 4);
    const float* src = (m ? tW2 : sW2) + layer * 4096 + row * 64 + kb;
    float4 a = *(const float4*)src;
    float4 b = *(const float4*)(src + 4);
    uint4 v = make_uint4(pkbf(a.x, a.y), pkbf(a.z, a.w), pkbf(b.x, b.y), pkbf(b.z, b.w));
    sm->afr[m][f][l] = v;
  }
}

__global__ __launch_bounds__(BLOCK)
__attribute__((amdgpu_waves_per_eu(4, 4)))
void ihll_kernel(
    const float* __restrict__ pred, const float* __restrict__ targ, const float* __restrict__ twp,
    const float* __restrict__ sW1, const float* __restrict__ sB1, const float* __restrict__ sW2,
    const float* __restrict__ sB2, const float* __restrict__ sW3, const float* __restrict__ sB3,
    const float* __restrict__ tW1, const float* __restrict__ tB1, const float* __restrict__ tW2,
    const float* __restrict__ tB2, const float* __restrict__ tW3, const float* __restrict__ tB3,
    float* __restrict__ out, int M) {
  __shared__ SM sm;
  const int tid  = threadIdx.x;
  const int lane = tid & 63, wave = tid >> 6;
  const int pr   = lane & 15, g = lane >> 4;
  const int pbase = blockIdx.x * PTS_BLK;
  const f2_t k01 = {0.01f, 0.01f};

  // ---- stage per-layer small tables (all 6 layers, once), all fp32 ----
  for (int idx = tid; idx < 768; idx += BLOCK) {
    int i = idx >> 7, r = idx & 127, m = r >> 6, j = r & 63;
    int jo = i & 1, jm = jo ^ 1;                    // MASK[i]: i even -> m=[0,1] (jm=1, jo=0)
    const float* w1 = m ? tW1 : sW1;  const float* b1 = m ? tB1 : sB1;
    const float* w3 = m ? tW3 : sW3;  const float* b2 = m ? tB2 : sB2;
    sm.c1[i][m][j]  = w1[i * 128 + j * 2 + jm];
    sm.b1[i][m][j]  = b1[i * 64 + j];
    sm.b2f[i][m][j] = b2[i * 64 + j];
    sm.w3f[i][m][j] = w3[i * 128 + jo * 64 + j];
  }
  // ---- stage point state: z = error (base term recomputed in epilogue) ----
  #pragma unroll
  for (int it = 0; it < 2; ++it) {
    int idx = tid + it * BLOCK;
    int P = pbase + idx;
    float2 zs = make_float2(0.f, 0.f);
    if (P < M) {
      float4 p4 = ((const float4*)pred)[P];
      float2 t2 = ((const float2*)targ)[P];
      float s0 = sqrtf(fabsf(p4.z)), s1 = sqrtf(fabsf(p4.w));
      zs.x = (p4.x - t2.x) / (s0 + 1e-9f);
      zs.y = (p4.y - t2.y) / (s1 + 1e-9f);
    }
    sm.z01[idx] = zs;
    sm.ld[idx]  = 0.f;
  }
  stage_layer(&sm, sW2, tW2, 5, tid);   // first layer processed is i=5
  __syncthreads();

  const int wbase = wave * (T_TILES * 16);

  // ---- layer loop: i = 5..0 ----
  #pragma unroll 1
  for (int li = 0; li < 6; ++li) {
    const int i = 5 - li;
    const int jo = i & 1;             // component written this layer
    const bool upd0 = (jo == 0);      // jo==0: input comp is z1, output z0

    // per-layer constants (allocator keeps or cheaply re-reads LDS)
    uint4 af[2][8];
    #pragma unroll
    for (int m = 0; m < 2; ++m)
      #pragma unroll
      for (int f = 0; f < 8; ++f)
        af[m][f] = sm.afr[m][f][lane];

    f2_t c1p[2][8], b1p[2][8];
    #pragma unroll
    for (int m = 0; m < 2; ++m)
      #pragma unroll
      for (int q = 0; q < 2; ++q) {
        f4_t ca = *(const f4_t*)&sm.c1[i][m][q * 32 + 8 * g];
        f4_t cb = *(const f4_t*)&sm.c1[i][m][q * 32 + 8 * g + 4];
        f4_t ba = *(const f4_t*)&sm.b1[i][m][q * 32 + 8 * g];
        f4_t bb4 = *(const f4_t*)&sm.b1[i][m][q * 32 + 8 * g + 4];
        c1p[m][q * 4 + 0] = (f2_t){ca[0], ca[1]};  c1p[m][q * 4 + 1] = (f2_t){ca[2], ca[3]};
        c1p[m][q * 4 + 2] = (f2_t){cb[0], cb[1]};  c1p[m][q * 4 + 3] = (f2_t){cb[2], cb[3]};
        b1p[m][q * 4 + 0] = (f2_t){ba[0], ba[1]};  b1p[m][q * 4 + 1] = (f2_t){ba[2], ba[3]};
        b1p[m][q * 4 + 2] = (f2_t){bb4[0], bb4[1]}; b1p[m][q * 4 + 3] = (f2_t){bb4[2], bb4[3]};
      }
    f2_t w3p[2][8];
    #pragma unroll
    for (int m = 0; m < 2; ++m)
      #pragma unroll
      for (int n = 0; n < 4; ++n) {
        f4_t wv = *(const f4_t*)&sm.w3f[i][m][n * 16 + 4 * g];
        w3p[m][2 * n]     = (f2_t){wv[0], wv[1]};
        w3p[m][2 * n + 1] = (f2_t){wv[2], wv[3]};
      }
    const float b3s = sB3[i * 2 + jo];
    const float b3t = tB3[i * 2 + jo];

    #pragma unroll 1
    for (int t = 0; t < T_TILES; ++t) {
      const int widx = wbase + t * 16 + pr;
      float2 zv = sm.z01[widx];
      const float zin = upd0 ? zv.y : zv.x;     // masked-in component z[jm]
      const f2_t zin2 = {zin, zin};
      float pre[2];
      #pragma unroll
      for (int m = 0; m < 2; ++m) {
        f4_t acc[4];
        #pragma unroll
        for (int q = 0; q < 2; ++q) {
          // layer 1: h1 = leaky(w1[:,jm]*zin + b1), 8 k-slots -> bf16 B-frag
          unsigned bb[4];
          #pragma unroll
          for (int e2 = 0; e2 < 4; ++e2) {
            f2_t h = pk_fma(c1p[m][q * 4 + e2], zin2, b1p[m][q * 4 + e2]);
            h = pk_leaky(h, k01);
            bb[e2] = pkbf(h.x, h.y);
          }
          bfrag_t B = __builtin_bit_cast(bfrag_t, make_uint4(bb[0], bb[1], bb[2], bb[3]));
          #pragma unroll
          for (int n = 0; n < 4; ++n) {
            // fold b2 into the first MFMA's C operand, read straight from LDS
            f4_t c = (q == 0) ? *(const f4_t*)&sm.b2f[i][m][n * 16 + 4 * g] : acc[n];
            acc[n] = __builtin_amdgcn_mfma_f32_16x16x32_bf16(
                __builtin_bit_cast(bfrag_t, af[m][q * 4 + n]), B, c, 0, 0, 0);
          }
        }
        // layer 3: leaky(h2) . w3 via two independent packed chains
        f2_t pa = {0.f, 0.f}, pb = {0.f, 0.f};
        #pragma unroll
        for (int n = 0; n < 4; ++n) {
          f2_t lo = __builtin_shufflevector(acc[n], acc[n], 0, 1);
          f2_t hi = __builtin_shufflevector(acc[n], acc[n], 2, 3);
          lo = pk_leaky(lo, k01);
          pa = pk_fma(lo, w3p[m][2 * n], pa);
          hi = pk_leaky(hi, k01);
          pb = pk_fma(hi, w3p[m][2 * n + 1], pb);
        }
        float part = (pa.x + pa.y) + (pb.x + pb.y);
        part += __shfl_xor(part, 16);
        part += __shfl_xor(part, 32);
        pre[m] = part;
      }
      // coupling update (identical across the 4 lane-groups)
      float esv = __expf(2.f * (pre[0] + b3s));
      float sv  = 1.f - 2.f / (esv + 1.f);          // tanh
      float tv  = pre[1] + b3t;
      float zo  = upd0 ? zv.x : zv.y;
      float zn  = (zo - tv) * __expf(-sv);
      if (upd0) zv.x = zn; else zv.y = zn;
      if (g == 0) {
        sm.z01[widx] = zv;
        sm.ld[widx] -= sv;
      }
    }
    __syncthreads();
    if (li < 5) {
      stage_layer(&sm, sW2, tW2, i - 1, tid);
      __syncthreads();
    }
  }

  // ---- epilogue: recompute base term from global, add prior + logdet, reduce ----
  float csum = 0.f;
  #pragma unroll
  for (int it = 0; it < 2; ++it) {
    int idx = tid + it * BLOCK;
    int P = pbase + idx;
    if (P < M) {
      float4 p4 = ((const float4*)pred)[P];
      float2 t2 = ((const float2*)targ)[P];
      float w   = twp[P];
      float s0 = sqrtf(fabsf(p4.z)), s1 = sqrtf(fabsf(p4.w));
      float e0 = (p4.x - t2.x) / (s0 + 1e-9f);
      float e1 = (p4.y - t2.y) / (s1 + 1e-9f);
      float bs = 2.f * (logf(s0) + logf(s1)) + TWO_LOG2 + fabsf(e0) + fabsf(e1);
      float2 zv = sm.z01[idx];
      float prior = -0.5f * (zv.x * zv.x + zv.y * zv.y) - LOG_2PI;
      float lphi  = prior + sm.ld[idx];
      csum += (bs - 2.f * lphi) * w;
    }
  }
  #pragma unroll
  for (int off = 1; off <= 32; off <<= 1)
    csum += __shfl_xor(csum, off);
  if (lane == 0) sm.wsum[wave] = csum;
  __syncthreads();
  if (tid == 0) {
    float tot = sm.wsum[0] + sm.wsum[1] + sm.wsum[2] + sm.wsum[3];
    atomicAdd(out, tot * (1.0f / 8192.0f));   // /pred.shape[0]
  }
}

extern "C" void kernel_launch(void* const* d_in, const int* in_sizes, int n_in,
                              void* d_out, int out_size, void* d_ws, size_t ws_size,
                              hipStream_t stream) {
  const float* pred = (const float*)d_in[0];
  const float* targ = (const float*)d_in[1];
  const float* twp  = (const float*)d_in[2];
  const float* sW1 = (const float*)d_in[3];  const float* sB1 = (const float*)d_in[4];
  const float* sW2 = (const float*)d_in[5];  const float* sB2 = (const float*)d_in[6];
  const float* sW3 = (const float*)d_in[7];  const float* sB3 = (const float*)d_in[8];
  const float* tW1 = (const float*)d_in[9];  const float* tB1 = (const float*)d_in[10];
  const float* tW2 = (const float*)d_in[11]; const float* tB2 = (const float*)d_in[12];
  const float* tW3 = (const float*)d_in[13]; const float* tB3 = (const float*)d_in[14];

  const int M = in_sizes[2];               // N*K points
  const int blocks = (M + PTS_BLK - 1) / PTS_BLK;

  hipMemsetAsync(d_out, 0, sizeof(float), stream);
  hipLaunchKernelGGL(ihll_kernel, dim3(blocks), dim3(BLOCK), 0, stream,
                     pred, targ, twp, sW1, sB1, sW2, sB2, sW3, sB3,
                     tW1, tB1, tW2, tB2, tW3, tB3, (float*)d_out, M);
}

// Round 6
// 357.955 us; speedup vs baseline: 3.9998x; 3.9998x over previous
//
#include <hip/hip_runtime.h>

typedef __attribute__((ext_vector_type(8))) short bfrag_t;   // 8 x bf16 (4 VGPRs)
typedef __attribute__((ext_vector_type(4))) float f4_t;
typedef __attribute__((ext_vector_type(2))) float f2_t;

#define LOG_2PI   1.8378770664093453f
#define TWO_LOG2  1.3862943611198906f
#define T_TILES   8            // 16-point tiles per wave
#define BLOCK     256          // 4 waves
#define PTS_BLK   512          // 4 waves * 8 tiles * 16 pts

struct SM {
  uint4    afr[2][8][64];      // 16KB [mlp][frag=q*4+n][lane] pre-swizzled bf16 W2 A-frags
  float2   z01[PTS_BLK];       // 4KB  per-point (z0, z1)
  float    ld[PTS_BLK];        // 2KB  per-point log-det accumulator
  float    pre0[PTS_BLK];      // 2KB  s-net pre-activation (m=0 pass -> m=1 pass, wave-private)
  float    c1[6][2][64];       // 3KB  w1[j][jm]
  float    b1[6][2][64];       // 3KB  b1[j]
  float    b2f[6][2][64];      // 3KB  b2[j] fp32 (MFMA C-init via ds_read_b128)
  float    w3f[6][2][64];      // 3KB  w3[jo][j] fp32
  float    wsum[4];
};                             // ~36.5KB -> 4 blocks/CU

__device__ __forceinline__ unsigned pkbf(float lo, float hi) {
  unsigned r;
  asm("v_cvt_pk_bf16_f32 %0, %1, %2" : "=v"(r) : "v"(lo), "v"(hi));
  return r;
}
__device__ __forceinline__ f2_t pk_fma(f2_t a, f2_t b, f2_t c) {
  f2_t d;
  asm("v_pk_fma_f32 %0, %1, %2, %3" : "=v"(d) : "v"(a), "v"(b), "v"(c));
  return d;
}
// leaky-relu on 2 lanes: packed mul + 2 scalar max (no v_pk_max_f32 on gfx950)
__device__ __forceinline__ f2_t pk_leaky(f2_t h, f2_t k01) {
  f2_t t, r;
  asm("v_pk_mul_f32 %0, %1, %2" : "=v"(t) : "v"(h), "v"(k01));
  r.x = fmaxf(h.x, t.x);
  r.y = fmaxf(h.y, t.y);
  return r;
}

// Stage one layer's W2 (both MLPs) into LDS as MFMA A-fragments (bf16).
// A-frag layout for mfma_f32_16x16x32_bf16: lane l holds A[16n + (l&15)][32q + 8*(l>>4) + e], e=0..7
__device__ __forceinline__ void stage_layer(SM* sm, const float* sW2, const float* tW2,
                                            int layer, int tid) {
  #pragma unroll
  for (int it = 0; it < 4; ++it) {
    int idx = tid + it * BLOCK;          // 0..1023
    int l = idx & 63, f = (idx >> 6) & 7, m = (idx >> 9) & 1;
    int n = f & 3, q = f >> 2;
    int row = 16 * n + (l & 15), kb = 32 * q + 8 * (l >> 4);
    const float* src = (m ? tW2 : sW2) + layer * 4096 + row * 64 + kb;
    float4 a = *(const float4*)src;
    float4 b = *(const float4*)(src + 4);
    uint4 v = make_uint4(pkbf(a.x, a.y), pkbf(a.z, a.w), pkbf(b.x, b.y), pkbf(b.z, b.w));
    sm->afr[m][f][l] = v;
  }
}

__global__ __launch_bounds__(BLOCK)
void ihll_kernel(
    const float* __restrict__ pred, const float* __restrict__ targ, const float* __restrict__ twp,
    const float* __restrict__ sW1, const float* __restrict__ sB1, const float* __restrict__ sW2,
    const float* __restrict__ sB2, const float* __restrict__ sW3, const float* __restrict__ sB3,
    const float* __restrict__ tW1, const float* __restrict__ tB1, const float* __restrict__ tW2,
    const float* __restrict__ tB2, const float* __restrict__ tW3, const float* __restrict__ tB3,
    float* __restrict__ out, int M) {
  __shared__ SM sm;
  const int tid  = threadIdx.x;
  const int lane = tid & 63, wave = tid >> 6;
  const int pr   = lane & 15, g = lane >> 4;
  const int pbase = blockIdx.x * PTS_BLK;
  const f2_t k01 = {0.01f, 0.01f};

  // ---- stage per-layer small tables (all 6 layers, once), all fp32 ----
  for (int idx = tid; idx < 768; idx += BLOCK) {
    int i = idx >> 7, r = idx & 127, m = r >> 6, j = r & 63;
    int jo = i & 1, jm = jo ^ 1;                    // MASK[i]: i even -> m=[0,1] (jm=1, jo=0)
    const float* w1 = m ? tW1 : sW1;  const float* b1 = m ? tB1 : sB1;
    const float* w3 = m ? tW3 : sW3;  const float* b2 = m ? tB2 : sB2;
    sm.c1[i][m][j]  = w1[i * 128 + j * 2 + jm];
    sm.b1[i][m][j]  = b1[i * 64 + j];
    sm.b2f[i][m][j] = b2[i * 64 + j];
    sm.w3f[i][m][j] = w3[i * 128 + jo * 64 + j];
  }
  // ---- stage point state: z = error (base term recomputed in epilogue) ----
  #pragma unroll
  for (int it = 0; it < 2; ++it) {
    int idx = tid + it * BLOCK;
    int P = pbase + idx;
    float2 zs = make_float2(0.f, 0.f);
    if (P < M) {
      float4 p4 = ((const float4*)pred)[P];
      float2 t2 = ((const float2*)targ)[P];
      float s0 = sqrtf(fabsf(p4.z)), s1 = sqrtf(fabsf(p4.w));
      zs.x = (p4.x - t2.x) / (s0 + 1e-9f);
      zs.y = (p4.y - t2.y) / (s1 + 1e-9f);
    }
    sm.z01[idx] = zs;
    sm.ld[idx]  = 0.f;
  }
  stage_layer(&sm, sW2, tW2, 5, tid);   // first layer processed is i=5
  __syncthreads();

  const int wbase = wave * (T_TILES * 16);

  // ---- layer loop: i = 5..0 ----
  #pragma unroll 1
  for (int li = 0; li < 6; ++li) {
    const int i = 5 - li;
    const int jo = i & 1;             // component written this layer
    const bool upd0 = (jo == 0);      // jo==0: input comp is z1, output z0
    const float b3s = sB3[i * 2 + jo];
    const float b3t = tB3[i * 2 + jo];

    // ---- two passes: m=0 (s-net, store pre0), m=1 (t-net + coupling update) ----
    // Halved resident set (~110 VGPR) so per-layer constants stay in registers
    // across the 8-tile loop instead of being re-read from LDS every tile.
    #pragma unroll 1
    for (int m = 0; m < 2; ++m) {
      uint4 af[8];
      #pragma unroll
      for (int f = 0; f < 8; ++f)
        af[f] = sm.afr[m][f][lane];

      f2_t c1p[8], b1p[8];
      #pragma unroll
      for (int q = 0; q < 2; ++q) {
        f4_t ca  = *(const f4_t*)&sm.c1[i][m][q * 32 + 8 * g];
        f4_t cb  = *(const f4_t*)&sm.c1[i][m][q * 32 + 8 * g + 4];
        f4_t ba  = *(const f4_t*)&sm.b1[i][m][q * 32 + 8 * g];
        f4_t bb4 = *(const f4_t*)&sm.b1[i][m][q * 32 + 8 * g + 4];
        c1p[q * 4 + 0] = (f2_t){ca[0], ca[1]};   c1p[q * 4 + 1] = (f2_t){ca[2], ca[3]};
        c1p[q * 4 + 2] = (f2_t){cb[0], cb[1]};   c1p[q * 4 + 3] = (f2_t){cb[2], cb[3]};
        b1p[q * 4 + 0] = (f2_t){ba[0], ba[1]};   b1p[q * 4 + 1] = (f2_t){ba[2], ba[3]};
        b1p[q * 4 + 2] = (f2_t){bb4[0], bb4[1]}; b1p[q * 4 + 3] = (f2_t){bb4[2], bb4[3]};
      }
      f2_t w3p[8];
      #pragma unroll
      for (int n = 0; n < 4; ++n) {
        f4_t wv = *(const f4_t*)&sm.w3f[i][m][n * 16 + 4 * g];
        w3p[2 * n]     = (f2_t){wv[0], wv[1]};
        w3p[2 * n + 1] = (f2_t){wv[2], wv[3]};
      }

      #pragma unroll 1
      for (int t = 0; t < T_TILES; ++t) {
        const int widx = wbase + t * 16 + pr;
        float2 zv = sm.z01[widx];
        const float zin = upd0 ? zv.y : zv.x;     // masked-in component z[jm]
        const f2_t zin2 = {zin, zin};

        f4_t acc[4];
        #pragma unroll
        for (int q = 0; q < 2; ++q) {
          // layer 1: h1 = leaky(w1[:,jm]*zin + b1), 8 k-slots -> bf16 B-frag
          unsigned bb[4];
          #pragma unroll
          for (int e2 = 0; e2 < 4; ++e2) {
            f2_t h = pk_fma(c1p[q * 4 + e2], zin2, b1p[q * 4 + e2]);
            h = pk_leaky(h, k01);
            bb[e2] = pkbf(h.x, h.y);
          }
          bfrag_t B = __builtin_bit_cast(bfrag_t, make_uint4(bb[0], bb[1], bb[2], bb[3]));
          #pragma unroll
          for (int n = 0; n < 4; ++n) {
            // fold b2 into the first MFMA's C operand, read straight from LDS
            f4_t c = (q == 0) ? *(const f4_t*)&sm.b2f[i][m][n * 16 + 4 * g] : acc[n];
            acc[n] = __builtin_amdgcn_mfma_f32_16x16x32_bf16(
                __builtin_bit_cast(bfrag_t, af[q * 4 + n]), B, c, 0, 0, 0);
          }
        }
        // layer 3: leaky(h2) . w3 via two independent packed chains
        f2_t pa = {0.f, 0.f}, pb = {0.f, 0.f};
        #pragma unroll
        for (int n = 0; n < 4; ++n) {
          f2_t lo = __builtin_shufflevector(acc[n], acc[n], 0, 1);
          f2_t hi = __builtin_shufflevector(acc[n], acc[n], 2, 3);
          lo = pk_leaky(lo, k01);
          pa = pk_fma(lo, w3p[2 * n], pa);
          hi = pk_leaky(hi, k01);
          pb = pk_fma(hi, w3p[2 * n + 1], pb);
        }
        float part = (pa.x + pa.y) + (pb.x + pb.y);
        part += __shfl_xor(part, 16);
        part += __shfl_xor(part, 32);

        if (m == 0) {
          // s-net pre-activation -> LDS (wave-private range; no barrier needed)
          if (g == 0) sm.pre0[widx] = part;
        } else {
          // coupling update (computed wave-uniform; g==0 writes)
          float p0  = sm.pre0[widx];
          float esv = __expf(2.f * (p0 + b3s));
          float sv  = 1.f - 2.f / (esv + 1.f);          // tanh
          float tv  = part + b3t;
          float zo  = upd0 ? zv.x : zv.y;
          float zn  = (zo - tv) * __expf(-sv);
          if (upd0) zv.x = zn; else zv.y = zn;
          if (g == 0) {
            sm.z01[widx] = zv;
            sm.ld[widx] -= sv;
          }
        }
      }
    }
    __syncthreads();
    if (li < 5) {
      stage_layer(&sm, sW2, tW2, i - 1, tid);
      __syncthreads();
    }
  }

  // ---- epilogue: recompute base term from global, add prior + logdet, reduce ----
  float csum = 0.f;
  #pragma unroll
  for (int it = 0; it < 2; ++it) {
    int idx = tid + it * BLOCK;
    int P = pbase + idx;
    if (P < M) {
      float4 p4 = ((const float4*)pred)[P];
      float2 t2 = ((const float2*)targ)[P];
      float w   = twp[P];
      float s0 = sqrtf(fabsf(p4.z)), s1 = sqrtf(fabsf(p4.w));
      float e0 = (p4.x - t2.x) / (s0 + 1e-9f);
      float e1 = (p4.y - t2.y) / (s1 + 1e-9f);
      float bs = 2.f * (logf(s0) + logf(s1)) + TWO_LOG2 + fabsf(e0) + fabsf(e1);
      float2 zv = sm.z01[idx];
      float prior = -0.5f * (zv.x * zv.x + zv.y * zv.y) - LOG_2PI;
      float lphi  = prior + sm.ld[idx];
      csum += (bs - 2.f * lphi) * w;
    }
  }
  #pragma unroll
  for (int off = 1; off <= 32; off <<= 1)
    csum += __shfl_xor(csum, off);
  if (lane == 0) sm.wsum[wave] = csum;
  __syncthreads();
  if (tid == 0) {
    float tot = sm.wsum[0] + sm.wsum[1] + sm.wsum[2] + sm.wsum[3];
    atomicAdd(out, tot * (1.0f / 8192.0f));   // /pred.shape[0]
  }
}

extern "C" void kernel_launch(void* const* d_in, const int* in_sizes, int n_in,
                              void* d_out, int out_size, void* d_ws, size_t ws_size,
                              hipStream_t stream) {
  const float* pred = (const float*)d_in[0];
  const float* targ = (const float*)d_in[1];
  const float* twp  = (const float*)d_in[2];
  const float* sW1 = (const float*)d_in[3];  const float* sB1 = (const float*)d_in[4];
  const float* sW2 = (const float*)d_in[5];  const float* sB2 = (const float*)d_in[6];
  const float* sW3 = (const float*)d_in[7];  const float* sB3 = (const float*)d_in[8];
  const float* tW1 = (const float*)d_in[9];  const float* tB1 = (const float*)d_in[10];
  const float* tW2 = (const float*)d_in[11]; const float* tB2 = (const float*)d_in[12];
  const float* tW3 = (const float*)d_in[13]; const float* tB3 = (const float*)d_in[14];

  const int M = in_sizes[2];               // N*K points
  const int blocks = (M + PTS_BLK - 1) / PTS_BLK;

  hipMemsetAsync(d_out, 0, sizeof(float), stream);
  hipLaunchKernelGGL(ihll_kernel, dim3(blocks), dim3(BLOCK), 0, stream,
                     pred, targ, twp, sW1, sB1, sW2, sB2, sW3, sB3,
                     tW1, tB1, tW2, tB2, tW3, tB3, (float*)d_out, M);
}

// Round 7
// 356.902 us; speedup vs baseline: 4.0116x; 1.0030x over previous
//
#include <hip/hip_runtime.h>

typedef __attribute__((ext_vector_type(8))) short bfrag_t;     // 8 x bf16 (4 VGPRs)
typedef __attribute__((ext_vector_type(4))) float f4_t;
typedef __attribute__((ext_vector_type(2))) float f2_t;
typedef __attribute__((ext_vector_type(4))) unsigned u4_t;

#define LOG_2PI   1.8378770664093453f
#define TWO_LOG2  1.3862943611198906f
#define T_TILES   8            // 16-point tiles per wave
#define BLOCK     256          // 4 waves
#define PTS_BLK   512          // 4 waves * 8 tiles * 16 pts

__device__ __forceinline__ unsigned pkbf(float lo, float hi) {
  unsigned r;
  asm("v_cvt_pk_bf16_f32 %0, %1, %2" : "=v"(r) : "v"(lo), "v"(hi));
  return r;
}
__device__ __forceinline__ f2_t pk_fma(f2_t a, f2_t b, f2_t c) {
  f2_t d;
  asm("v_pk_fma_f32 %0, %1, %2, %3" : "=v"(d) : "v"(a), "v"(b), "v"(c));
  return d;
}
// leaky-relu on 2 lanes: packed mul + 2 scalar max (no v_pk_max_f32 on gfx950)
__device__ __forceinline__ f2_t pk_leaky(f2_t h, f2_t k01) {
  f2_t t, r;
  asm("v_pk_mul_f32 %0, %1, %2" : "=v"(t) : "v"(h), "v"(k01));
  r.x = fmaxf(h.x, t.x);
  r.y = fmaxf(h.y, t.y);
  return r;
}
// opaque register pin: forbids the allocator from sinking/rematerializing x
__device__ __forceinline__ void pin_u4(u4_t& x) { asm volatile("" : "+v"(x)); }
__device__ __forceinline__ void pin_f2(f2_t& x) { asm volatile("" : "+v"(x)); }

// Stage one layer's W2 (both MLPs) into LDS as MFMA A-fragments (bf16).
// A-frag layout for mfma_f32_16x16x32_bf16: lane l holds A[16n + (l&15)][32q + 8*(l>>4) + e], e=0..7
__device__ __forceinline__ void stage_layer(u4_t* afr, const float* sW2, const float* tW2,
                                            int layer, int tid) {
  #pragma unroll
  for (int it = 0; it < 4; ++it) {
    int idx = tid + it * BLOCK;          // 0..1023
    int l = idx & 63, f = (idx >> 6) & 7, m = (idx >> 9) & 1;
    int n = f & 3, q = f >> 2;
    int row = 16 * n + (l & 15), kb = 32 * q + 8 * (l >> 4);
    const float* src = (m ? tW2 : sW2) + layer * 4096 + row * 64 + kb;
    float4 a = *(const float4*)src;
    float4 b = *(const float4*)(src + 4);
    afr[(m * 8 + f) * 64 + l] =
        (u4_t){pkbf(a.x, a.y), pkbf(a.z, a.w), pkbf(b.x, b.y), pkbf(b.z, b.w)};
  }
}

__global__ __launch_bounds__(BLOCK)
void ihll_kernel(
    const float* __restrict__ pred, const float* __restrict__ targ, const float* __restrict__ twp,
    const float* __restrict__ sW1, const float* __restrict__ sB1, const float* __restrict__ sW2,
    const float* __restrict__ sB2, const float* __restrict__ sW3, const float* __restrict__ sB3,
    const float* __restrict__ tW1, const float* __restrict__ tB1, const float* __restrict__ tW2,
    const float* __restrict__ tB2, const float* __restrict__ tW3, const float* __restrict__ tB3,
    float* __restrict__ out, int M) {
  // separate __shared__ objects: distinct objects cannot alias, so the
  // per-layer constant ds_reads are loop-invariant and hoistable past the
  // runtime-indexed zld/pre0 stores (the single-struct version defeated AA).
  __shared__ u4_t   afr[2 * 8 * 64];     // 16KB pre-swizzled bf16 W2 A-frags
  __shared__ float4 zld[PTS_BLK];        // 8KB  (z0, z1, ldet, pad)
  __shared__ float  pre0v[PTS_BLK];      // 2KB  s-net preact (m=0 -> m=1, wave-private)
  __shared__ float  c1s[6][2][64];       // 3KB  w1[j][jm]
  __shared__ float  b1s[6][2][64];       // 3KB  b1[j]
  __shared__ float  b2s[6][2][64];       // 3KB  b2[j]
  __shared__ float  w3s[6][2][64];       // 3KB  w3[jo][j]
  __shared__ float  wsum[4];

  const int tid  = threadIdx.x;
  const int lane = tid & 63, wave = tid >> 6;
  const int pr   = lane & 15, g = lane >> 4;
  const int pbase = blockIdx.x * PTS_BLK;
  const f2_t k01 = {0.01f, 0.01f};

  // ---- stage per-layer small tables (all 6 layers, once), all fp32 ----
  for (int idx = tid; idx < 768; idx += BLOCK) {
    int i = idx >> 7, r = idx & 127, m = r >> 6, j = r & 63;
    int jo = i & 1, jm = jo ^ 1;                    // MASK[i]: i even -> m=[0,1] (jm=1, jo=0)
    const float* w1 = m ? tW1 : sW1;  const float* b1 = m ? tB1 : sB1;
    const float* w3 = m ? tW3 : sW3;  const float* b2 = m ? tB2 : sB2;
    c1s[i][m][j] = w1[i * 128 + j * 2 + jm];
    b1s[i][m][j] = b1[i * 64 + j];
    b2s[i][m][j] = b2[i * 64 + j];
    w3s[i][m][j] = w3[i * 128 + jo * 64 + j];
  }
  // ---- stage point state: z = error (base term recomputed in epilogue) ----
  #pragma unroll
  for (int it = 0; it < 2; ++it) {
    int idx = tid + it * BLOCK;
    int P = pbase + idx;
    float4 zs = make_float4(0.f, 0.f, 0.f, 0.f);
    if (P < M) {
      float4 p4 = ((const float4*)pred)[P];
      float2 t2 = ((const float2*)targ)[P];
      float s0 = sqrtf(fabsf(p4.z)), s1 = sqrtf(fabsf(p4.w));
      zs.x = (p4.x - t2.x) / (s0 + 1e-9f);
      zs.y = (p4.y - t2.y) / (s1 + 1e-9f);
    }
    zld[idx] = zs;
  }
  stage_layer(afr, sW2, tW2, 5, tid);   // first layer processed is i=5
  __syncthreads();

  const int wbase = wave * (T_TILES * 16);

  // ---- layer loop: i = 5..0 ----
  #pragma unroll 1
  for (int li = 0; li < 6; ++li) {
    const int i = 5 - li;
    const int jo = i & 1;             // component written this layer
    const bool upd0 = (jo == 0);      // jo==0: input comp is z1, output z0
    const float b3s = sB3[i * 2 + jo];
    const float b3t = tB3[i * 2 + jo];

    // ---- two passes: m=0 (s-net, store pre0), m=1 (t-net + coupling update) ----
    #pragma unroll 1
    for (int m = 0; m < 2; ++m) {
      // per-layer constants: hoisted once, PINNED resident (~80 VGPR)
      u4_t af[8];
      #pragma unroll
      for (int f = 0; f < 8; ++f) {
        af[f] = afr[(m * 8 + f) * 64 + lane];
        pin_u4(af[f]);
      }
      f2_t c1p[8], b1p[8];
      #pragma unroll
      for (int q = 0; q < 2; ++q) {
        f4_t ca  = *(const f4_t*)&c1s[i][m][q * 32 + 8 * g];
        f4_t cb  = *(const f4_t*)&c1s[i][m][q * 32 + 8 * g + 4];
        f4_t ba  = *(const f4_t*)&b1s[i][m][q * 32 + 8 * g];
        f4_t bb4 = *(const f4_t*)&b1s[i][m][q * 32 + 8 * g + 4];
        c1p[q * 4 + 0] = (f2_t){ca[0], ca[1]};   c1p[q * 4 + 1] = (f2_t){ca[2], ca[3]};
        c1p[q * 4 + 2] = (f2_t){cb[0], cb[1]};   c1p[q * 4 + 3] = (f2_t){cb[2], cb[3]};
        b1p[q * 4 + 0] = (f2_t){ba[0], ba[1]};   b1p[q * 4 + 1] = (f2_t){ba[2], ba[3]};
        b1p[q * 4 + 2] = (f2_t){bb4[0], bb4[1]}; b1p[q * 4 + 3] = (f2_t){bb4[2], bb4[3]};
      }
      #pragma unroll
      for (int e = 0; e < 8; ++e) { pin_f2(c1p[e]); pin_f2(b1p[e]); }
      f2_t w3p[8];
      #pragma unroll
      for (int n = 0; n < 4; ++n) {
        f4_t wv = *(const f4_t*)&w3s[i][m][n * 16 + 4 * g];
        w3p[2 * n]     = (f2_t){wv[0], wv[1]};
        w3p[2 * n + 1] = (f2_t){wv[2], wv[3]};
        pin_f2(w3p[2 * n]); pin_f2(w3p[2 * n + 1]);
      }

      #pragma unroll 1
      for (int t = 0; t < T_TILES; ++t) {
        const int widx = wbase + t * 16 + pr;
        float4 zv = zld[widx];
        const float zin = upd0 ? zv.y : zv.x;     // masked-in component z[jm]
        const f2_t zin2 = {zin, zin};

        f4_t acc[4];
        #pragma unroll
        for (int q = 0; q < 2; ++q) {
          // layer 1: h1 = leaky(w1[:,jm]*zin + b1), 8 k-slots -> bf16 B-frag
          unsigned bb[4];
          #pragma unroll
          for (int e2 = 0; e2 < 4; ++e2) {
            f2_t h = pk_fma(c1p[q * 4 + e2], zin2, b1p[q * 4 + e2]);
            h = pk_leaky(h, k01);
            bb[e2] = pkbf(h.x, h.y);
          }
          bfrag_t B = __builtin_bit_cast(bfrag_t, make_uint4(bb[0], bb[1], bb[2], bb[3]));
          #pragma unroll
          for (int n = 0; n < 4; ++n) {
            // fold b2 into the first MFMA's C operand (loop-invariant LDS read,
            // hoistable now that b2s is a distinct object)
            f4_t c = (q == 0) ? *(const f4_t*)&b2s[i][m][n * 16 + 4 * g] : acc[n];
            acc[n] = __builtin_amdgcn_mfma_f32_16x16x32_bf16(
                __builtin_bit_cast(bfrag_t, af[q * 4 + n]), B, c, 0, 0, 0);
          }
        }
        // layer 3: leaky(h2) . w3 via two independent packed chains
        f2_t pa = {0.f, 0.f}, pb = {0.f, 0.f};
        #pragma unroll
        for (int n = 0; n < 4; ++n) {
          f2_t lo = __builtin_shufflevector(acc[n], acc[n], 0, 1);
          f2_t hi = __builtin_shufflevector(acc[n], acc[n], 2, 3);
          lo = pk_leaky(lo, k01);
          pa = pk_fma(lo, w3p[2 * n], pa);
          hi = pk_leaky(hi, k01);
          pb = pk_fma(hi, w3p[2 * n + 1], pb);
        }
        float part = (pa.x + pa.y) + (pb.x + pb.y);
        part += __shfl_xor(part, 16);
        part += __shfl_xor(part, 32);

        if (m == 0) {
          if (g == 0) pre0v[widx] = part;   // wave-private range; no barrier
        } else {
          float p0  = pre0v[widx];
          float esv = __expf(2.f * (p0 + b3s));
          float sv  = 1.f - 2.f / (esv + 1.f);          // tanh
          float tv  = part + b3t;
          float zo  = upd0 ? zv.x : zv.y;
          float zn  = (zo - tv) * __expf(-sv);
          if (upd0) zv.x = zn; else zv.y = zn;
          zv.z -= sv;
          if (g == 0) zld[widx] = zv;       // one b128 write: z and ldet together
        }
      }
    }
    __syncthreads();
    if (li < 5) {
      stage_layer(afr, sW2, tW2, i - 1, tid);
      __syncthreads();
    }
  }

  // ---- epilogue: recompute base term from global, add prior + logdet, reduce ----
  float csum = 0.f;
  #pragma unroll
  for (int it = 0; it < 2; ++it) {
    int idx = tid + it * BLOCK;
    int P = pbase + idx;
    if (P < M) {
      float4 p4 = ((const float4*)pred)[P];
      float2 t2 = ((const float2*)targ)[P];
      float w   = twp[P];
      float s0 = sqrtf(fabsf(p4.z)), s1 = sqrtf(fabsf(p4.w));
      float e0 = (p4.x - t2.x) / (s0 + 1e-9f);
      float e1 = (p4.y - t2.y) / (s1 + 1e-9f);
      float bs = 2.f * (logf(s0) + logf(s1)) + TWO_LOG2 + fabsf(e0) + fabsf(e1);
      float4 zv = zld[idx];
      float prior = -0.5f * (zv.x * zv.x + zv.y * zv.y) - LOG_2PI;
      float lphi  = prior + zv.z;
      csum += (bs - 2.f * lphi) * w;
    }
  }
  #pragma unroll
  for (int off = 1; off <= 32; off <<= 1)
    csum += __shfl_xor(csum, off);
  if (lane == 0) wsum[wave] = csum;
  __syncthreads();
  if (tid == 0) {
    float tot = wsum[0] + wsum[1] + wsum[2] + wsum[3];
    atomicAdd(out, tot * (1.0f / 8192.0f));   // /pred.shape[0]
  }
}

extern "C" void kernel_launch(void* const* d_in, const int* in_sizes, int n_in,
                              void* d_out, int out_size, void* d_ws, size_t ws_size,
                              hipStream_t stream) {
  const float* pred = (const float*)d_in[0];
  const float* targ = (const float*)d_in[1];
  const float* twp  = (const float*)d_in[2];
  const float* sW1 = (const float*)d_in[3];  const float* sB1 = (const float*)d_in[4];
  const float* sW2 = (const float*)d_in[5];  const float* sB2 = (const float*)d_in[6];
  const float* sW3 = (const float*)d_in[7];  const float* sB3 = (const float*)d_in[8];
  const float* tW1 = (const float*)d_in[9];  const float* tB1 = (const float*)d_in[10];
  const float* tW2 = (const float*)d_in[11]; const float* tB2 = (const float*)d_in[12];
  const float* tW3 = (const float*)d_in[13]; const float* tB3 = (const float*)d_in[14];

  const int M = in_sizes[2];               // N*K points
  const int blocks = (M + PTS_BLK - 1) / PTS_BLK;

  hipMemsetAsync(d_out, 0, sizeof(float), stream);
  hipLaunchKernelGGL(ihll_kernel, dim3(blocks), dim3(BLOCK), 0, stream,
                     pred, targ, twp, sW1, sB1, sW2, sB2, sW3, sB3,
                     tW1, tB1, tW2, tB2, tW3, tB3, (float*)d_out, M);
}

// Round 8
// 299.271 us; speedup vs baseline: 4.7841x; 1.1926x over previous
//
#include <hip/hip_runtime.h>

typedef __attribute__((ext_vector_type(8))) short bfrag_t;     // 8 x bf16 (4 VGPRs)
typedef __attribute__((ext_vector_type(4))) float f4_t;
typedef __attribute__((ext_vector_type(4))) unsigned u4_t;

#define LOG_2PI   1.8378770664093453f
#define TWO_LOG2  1.3862943611198906f
#define T_TILES   8            // 16-point tiles per wave
#define BLOCK     256          // 4 waves
#define PTS_BLK   512          // 4 waves * 8 tiles * 16 pts

__device__ __forceinline__ unsigned pkbf(float lo, float hi) {
  unsigned r;
  asm("v_cvt_pk_bf16_f32 %0, %1, %2" : "=v"(r) : "v"(lo), "v"(hi));
  return r;
}
__device__ __forceinline__ float leaky(float h) { return fmaxf(h, 0.01f * h); }

// Stage one layer's W2 (both MLPs) into LDS as MFMA A-fragments (bf16).
// A-frag layout for mfma_f32_16x16x32_bf16: lane l holds A[16n + (l&15)][32q + 8*(l>>4) + e], e=0..7
__device__ __forceinline__ void stage_layer(u4_t* afr, const float* sW2, const float* tW2,
                                            int layer, int tid) {
  #pragma unroll
  for (int it = 0; it < 4; ++it) {
    int idx = tid + it * BLOCK;          // 0..1023
    int l = idx & 63, f = (idx >> 6) & 7, m = (idx >> 9) & 1;
    int n = f & 3, q = f >> 2;
    int row = 16 * n + (l & 15), kb = 32 * q + 8 * (l >> 4);
    const float* src = (m ? tW2 : sW2) + layer * 4096 + row * 64 + kb;
    float4 a = *(const float4*)src;
    float4 b = *(const float4*)(src + 4);
    afr[(m * 8 + f) * 64 + l] =
        (u4_t){pkbf(a.x, a.y), pkbf(a.z, a.w), pkbf(b.x, b.y), pkbf(b.z, b.w)};
  }
}

__global__ __launch_bounds__(BLOCK)
void ihll_kernel(
    const float* __restrict__ pred, const float* __restrict__ targ, const float* __restrict__ twp,
    const float* __restrict__ sW1, const float* __restrict__ sB1, const float* __restrict__ sW2,
    const float* __restrict__ sB2, const float* __restrict__ sW3, const float* __restrict__ sB3,
    const float* __restrict__ tW1, const float* __restrict__ tB1, const float* __restrict__ tW2,
    const float* __restrict__ tB2, const float* __restrict__ tW3, const float* __restrict__ tB3,
    float* __restrict__ out, int M) {
  __shared__ u4_t   afr[2 * 8 * 64];     // 16KB pre-swizzled bf16 W2 A-frags
  __shared__ float4 zld[PTS_BLK];        // 8KB  (z0, z1, ldet, pad)
  __shared__ float  pre0v[PTS_BLK];      // 2KB  s-net preact (m=0 -> m=1, wave-private)
  __shared__ float  c1s[6][2][64];       // 3KB  w1[j][jm]
  __shared__ float  b1s[6][2][64];       // 3KB  b1[j]
  __shared__ float  b2s[6][2][64];       // 3KB  b2[j]
  __shared__ float  w3s[6][2][64];       // 3KB  w3[jo][j]
  __shared__ float  wsum[4];

  const int tid  = threadIdx.x;
  const int lane = tid & 63, wave = tid >> 6;
  const int pr   = lane & 15, g = lane >> 4;
  const int pbase = blockIdx.x * PTS_BLK;

  // ---- stage per-layer small tables (all 6 layers, once), all fp32 ----
  for (int idx = tid; idx < 768; idx += BLOCK) {
    int i = idx >> 7, r = idx & 127, m = r >> 6, j = r & 63;
    int jo = i & 1, jm = jo ^ 1;                    // MASK[i]: i even -> m=[0,1] (jm=1, jo=0)
    const float* w1 = m ? tW1 : sW1;  const float* b1 = m ? tB1 : sB1;
    const float* w3 = m ? tW3 : sW3;  const float* b2 = m ? tB2 : sB2;
    c1s[i][m][j] = w1[i * 128 + j * 2 + jm];
    b1s[i][m][j] = b1[i * 64 + j];
    b2s[i][m][j] = b2[i * 64 + j];
    w3s[i][m][j] = w3[i * 128 + jo * 64 + j];
  }
  // ---- stage point state: z = error (base term recomputed in epilogue) ----
  #pragma unroll
  for (int it = 0; it < 2; ++it) {
    int idx = tid + it * BLOCK;
    int P = pbase + idx;
    float4 zs = make_float4(0.f, 0.f, 0.f, 0.f);
    if (P < M) {
      float4 p4 = ((const float4*)pred)[P];
      float2 t2 = ((const float2*)targ)[P];
      float s0 = sqrtf(fabsf(p4.z)), s1 = sqrtf(fabsf(p4.w));
      zs.x = (p4.x - t2.x) / (s0 + 1e-9f);
      zs.y = (p4.y - t2.y) / (s1 + 1e-9f);
    }
    zld[idx] = zs;
  }
  stage_layer(afr, sW2, tW2, 5, tid);   // first layer processed is i=5
  __syncthreads();

  const int wbase = wave * (T_TILES * 16);

  // ---- layer loop: i = 5..0 ----
  #pragma unroll 1
  for (int li = 0; li < 6; ++li) {
    const int i = 5 - li;
    const int jo = i & 1;             // component written this layer
    const bool upd0 = (jo == 0);      // jo==0: input comp is z1, output z0
    const float b3s = sB3[i * 2 + jo];
    const float b3t = tB3[i * 2 + jo];

    // ---- two passes: m=0 (s-net, store pre0), m=1 (t-net + coupling) ----
    #pragma unroll 1
    for (int m = 0; m < 2; ++m) {
      // A-frags: loaded once per pass (compiler may keep or re-read; amortized)
      u4_t af[8];
      #pragma unroll
      for (int f = 0; f < 8; ++f)
        af[f] = afr[(m * 8 + f) * 64 + lane];

      // t-loop processes TWO 16-pt tiles per iteration: the per-iteration
      // constant LDS reads (c1/b1/b2/w3) are shared across both sub-tiles,
      // halving per-point LDS traffic (the R7-measured binder).
      #pragma unroll 1
      for (int tt = 0; tt < T_TILES / 2; ++tt) {
        const int wA = wbase + (2 * tt) * 16 + pr;
        const int wB = wA + 16;

        // per-iteration constants (16 x ds_read_b128, shared by A and B)
        f4_t c1q[4], b1q[4], b2q[4], w3q[4];
        #pragma unroll
        for (int q = 0; q < 2; ++q) {
          c1q[2 * q]     = *(const f4_t*)&c1s[i][m][q * 32 + 8 * g];
          c1q[2 * q + 1] = *(const f4_t*)&c1s[i][m][q * 32 + 8 * g + 4];
          b1q[2 * q]     = *(const f4_t*)&b1s[i][m][q * 32 + 8 * g];
          b1q[2 * q + 1] = *(const f4_t*)&b1s[i][m][q * 32 + 8 * g + 4];
        }
        #pragma unroll
        for (int n = 0; n < 4; ++n) {
          b2q[n] = *(const f4_t*)&b2s[i][m][n * 16 + 4 * g];
          w3q[n] = *(const f4_t*)&w3s[i][m][n * 16 + 4 * g];
        }

        float4 zvA = zld[wA];
        float4 zvB = zld[wB];
        const float zinA = upd0 ? zvA.y : zvA.x;
        const float zinB = upd0 ? zvB.y : zvB.x;

        f4_t accA[4], accB[4];
        #pragma unroll
        for (int q = 0; q < 2; ++q) {
          const f4_t ca = c1q[2 * q], cb = c1q[2 * q + 1];
          const f4_t ba = b1q[2 * q], bb = b1q[2 * q + 1];
          // B-frag prep for both sub-tiles (scalar fp32; compiler schedules)
          unsigned pA[4], pB[4];
          {
            float h0 = leaky(fmaf(ca[0], zinA, ba[0]));
            float h1 = leaky(fmaf(ca[1], zinA, ba[1]));
            float h2 = leaky(fmaf(ca[2], zinA, ba[2]));
            float h3 = leaky(fmaf(ca[3], zinA, ba[3]));
            float h4 = leaky(fmaf(cb[0], zinA, bb[0]));
            float h5 = leaky(fmaf(cb[1], zinA, bb[1]));
            float h6 = leaky(fmaf(cb[2], zinA, bb[2]));
            float h7 = leaky(fmaf(cb[3], zinA, bb[3]));
            pA[0] = pkbf(h0, h1); pA[1] = pkbf(h2, h3);
            pA[2] = pkbf(h4, h5); pA[3] = pkbf(h6, h7);
          }
          {
            float h0 = leaky(fmaf(ca[0], zinB, ba[0]));
            float h1 = leaky(fmaf(ca[1], zinB, ba[1]));
            float h2 = leaky(fmaf(ca[2], zinB, ba[2]));
            float h3 = leaky(fmaf(ca[3], zinB, ba[3]));
            float h4 = leaky(fmaf(cb[0], zinB, bb[0]));
            float h5 = leaky(fmaf(cb[1], zinB, bb[1]));
            float h6 = leaky(fmaf(cb[2], zinB, bb[2]));
            float h7 = leaky(fmaf(cb[3], zinB, bb[3]));
            pB[0] = pkbf(h0, h1); pB[1] = pkbf(h2, h3);
            pB[2] = pkbf(h4, h5); pB[3] = pkbf(h6, h7);
          }
          bfrag_t BA = __builtin_bit_cast(bfrag_t, make_uint4(pA[0], pA[1], pA[2], pA[3]));
          bfrag_t BB = __builtin_bit_cast(bfrag_t, make_uint4(pB[0], pB[1], pB[2], pB[3]));
          #pragma unroll
          for (int n = 0; n < 4; ++n) {
            f4_t cA = (q == 0) ? b2q[n] : accA[n];   // b2 folded into first MFMA
            f4_t cB = (q == 0) ? b2q[n] : accB[n];
            accA[n] = __builtin_amdgcn_mfma_f32_16x16x32_bf16(
                __builtin_bit_cast(bfrag_t, af[q * 4 + n]), BA, cA, 0, 0, 0);
            accB[n] = __builtin_amdgcn_mfma_f32_16x16x32_bf16(
                __builtin_bit_cast(bfrag_t, af[q * 4 + n]), BB, cB, 0, 0, 0);
          }
        }
        // layer 3: leaky(h2) . w3 (scalar), then 4-group shuffle reduce
        float pa = 0.f, pb = 0.f;
        #pragma unroll
        for (int n = 0; n < 4; ++n) {
          #pragma unroll
          for (int r = 0; r < 4; ++r) {
            pa = fmaf(leaky(accA[n][r]), w3q[n][r], pa);
            pb = fmaf(leaky(accB[n][r]), w3q[n][r], pb);
          }
        }
        pa += __shfl_xor(pa, 16);  pa += __shfl_xor(pa, 32);
        pb += __shfl_xor(pb, 16);  pb += __shfl_xor(pb, 32);

        if (m == 0) {
          if (g == 0) { pre0v[wA] = pa; pre0v[wB] = pb; }   // wave-private
        } else {
          float p0A = pre0v[wA], p0B = pre0v[wB];
          float svA = 1.f - 2.f / (__expf(2.f * (p0A + b3s)) + 1.f);   // tanh
          float svB = 1.f - 2.f / (__expf(2.f * (p0B + b3s)) + 1.f);
          float tvA = pa + b3t, tvB = pb + b3t;
          float zoA = upd0 ? zvA.x : zvA.y;
          float zoB = upd0 ? zvB.x : zvB.y;
          float znA = (zoA - tvA) * __expf(-svA);
          float znB = (zoB - tvB) * __expf(-svB);
          if (upd0) { zvA.x = znA; zvB.x = znB; } else { zvA.y = znA; zvB.y = znB; }
          zvA.z -= svA;  zvB.z -= svB;
          if (g == 0) { zld[wA] = zvA; zld[wB] = zvB; }
        }
      }
    }
    __syncthreads();
    if (li < 5) {
      stage_layer(afr, sW2, tW2, i - 1, tid);
      __syncthreads();
    }
  }

  // ---- epilogue: recompute base term from global, add prior + logdet, reduce ----
  float csum = 0.f;
  #pragma unroll
  for (int it = 0; it < 2; ++it) {
    int idx = tid + it * BLOCK;
    int P = pbase + idx;
    if (P < M) {
      float4 p4 = ((const float4*)pred)[P];
      float2 t2 = ((const float2*)targ)[P];
      float w   = twp[P];
      float s0 = sqrtf(fabsf(p4.z)), s1 = sqrtf(fabsf(p4.w));
      float e0 = (p4.x - t2.x) / (s0 + 1e-9f);
      float e1 = (p4.y - t2.y) / (s1 + 1e-9f);
      float bs = 2.f * (logf(s0) + logf(s1)) + TWO_LOG2 + fabsf(e0) + fabsf(e1);
      float4 zv = zld[idx];
      float prior = -0.5f * (zv.x * zv.x + zv.y * zv.y) - LOG_2PI;
      float lphi  = prior + zv.z;
      csum += (bs - 2.f * lphi) * w;
    }
  }
  #pragma unroll
  for (int off = 1; off <= 32; off <<= 1)
    csum += __shfl_xor(csum, off);
  if (lane == 0) wsum[wave] = csum;
  __syncthreads();
  if (tid == 0) {
    float tot = wsum[0] + wsum[1] + wsum[2] + wsum[3];
    atomicAdd(out, tot * (1.0f / 8192.0f));   // /pred.shape[0]
  }
}

extern "C" void kernel_launch(void* const* d_in, const int* in_sizes, int n_in,
                              void* d_out, int out_size, void* d_ws, size_t ws_size,
                              hipStream_t stream) {
  const float* pred = (const float*)d_in[0];
  const float* targ = (const float*)d_in[1];
  const float* twp  = (const float*)d_in[2];
  const float* sW1 = (const float*)d_in[3];  const float* sB1 = (const float*)d_in[4];
  const float* sW2 = (const float*)d_in[5];  const float* sB2 = (const float*)d_in[6];
  const float* sW3 = (const float*)d_in[7];  const float* sB3 = (const float*)d_in[8];
  const float* tW1 = (const float*)d_in[9];  const float* tB1 = (const float*)d_in[10];
  const float* tW2 = (const float*)d_in[11]; const float* tB2 = (const float*)d_in[12];
  const float* tW3 = (const float*)d_in[13]; const float* tB3 = (const float*)d_in[14];

  const int M = in_sizes[2];               // N*K points
  const int blocks = (M + PTS_BLK - 1) / PTS_BLK;

  hipMemsetAsync(d_out, 0, sizeof(float), stream);
  hipLaunchKernelGGL(ihll_kernel, dim3(blocks), dim3(BLOCK), 0, stream,
                     pred, targ, twp, sW1, sB1, sW2, sB2, sW3, sB3,
                     tW1, tB1, tW2, tB2, tW3, tB3, (float*)d_out, M);
}

// Round 9
// 271.896 us; speedup vs baseline: 5.2658x; 1.1007x over previous
//
#include <hip/hip_runtime.h>

typedef __attribute__((ext_vector_type(8))) short bfrag_t;     // 8 x bf16 (4 VGPRs)
typedef __attribute__((ext_vector_type(4))) float f4_t;
typedef __attribute__((ext_vector_type(4))) unsigned u4_t;

#define LOG_2PI   1.8378770664093453f
#define TWO_LOG2  1.3862943611198906f
#define T_TILES   8            // 16-point tiles per wave
#define BLOCK     256          // 4 waves
#define PTS_BLK   512          // 4 waves * 8 tiles * 16 pts

__device__ __forceinline__ unsigned pkbf(float lo, float hi) {
  unsigned r;
  asm("v_cvt_pk_bf16_f32 %0, %1, %2" : "=v"(r) : "v"(lo), "v"(hi));
  return r;
}
__device__ __forceinline__ float leaky(float h) { return fmaxf(h, 0.01f * h); }

// Stage one layer's W2 (both MLPs) into LDS as MFMA A-fragments (bf16).
// A-frag layout for mfma_f32_16x16x32_bf16: lane l holds A[16n + (l&15)][32q + 8*(l>>4) + e], e=0..7
__device__ __forceinline__ void stage_layer(u4_t* afr, const float* sW2, const float* tW2,
                                            int layer, int tid) {
  #pragma unroll
  for (int it = 0; it < 4; ++it) {
    int idx = tid + it * BLOCK;          // 0..1023
    int l = idx & 63, f = (idx >> 6) & 7, m = (idx >> 9) & 1;
    int n = f & 3, q = f >> 2;
    int row = 16 * n + (l & 15), kb = 32 * q + 8 * (l >> 4);
    const float* src = (m ? tW2 : sW2) + layer * 4096 + row * 64 + kb;
    float4 a = *(const float4*)src;
    float4 b = *(const float4*)(src + 4);
    afr[(m * 8 + f) * 64 + l] =
        (u4_t){pkbf(a.x, a.y), pkbf(a.z, a.w), pkbf(b.x, b.y), pkbf(b.z, b.w)};
  }
}

__global__ __launch_bounds__(BLOCK)
void ihll_kernel(
    const float* __restrict__ pred, const float* __restrict__ targ, const float* __restrict__ twp,
    const float* __restrict__ sW1, const float* __restrict__ sB1, const float* __restrict__ sW2,
    const float* __restrict__ sB2, const float* __restrict__ sW3, const float* __restrict__ sB3,
    const float* __restrict__ tW1, const float* __restrict__ tB1, const float* __restrict__ tW2,
    const float* __restrict__ tB2, const float* __restrict__ tW3, const float* __restrict__ tB3,
    float* __restrict__ out, int M) {
  __shared__ u4_t   afr[2 * 8 * 64];     // 16KB pre-swizzled bf16 W2 A-frags
  __shared__ float4 zld[PTS_BLK];        // 8KB  (z0, z1, ldet, pad)
  __shared__ float  pre0v[PTS_BLK];      // 2KB  s-net preact (m=0 -> m=1, wave-private)
  __shared__ float  c1s[6][2][64];       // 3KB  w1[j][jm]
  __shared__ float  b1s[6][2][64];       // 3KB  b1[j]
  __shared__ unsigned wbs[6][2][64];     // 3KB  packed lo=bf16(b2[j]) hi=bf16(w3[jo][j])
  __shared__ float  wsum[4];

  const int tid  = threadIdx.x;
  const int lane = tid & 63, wave = tid >> 6;
  const int pr   = lane & 15, g = lane >> 4;
  const int pbase = blockIdx.x * PTS_BLK;

  // ---- stage per-layer small tables (all 6 layers, once) ----
  for (int idx = tid; idx < 768; idx += BLOCK) {
    int i = idx >> 7, r = idx & 127, m = r >> 6, j = r & 63;
    int jo = i & 1, jm = jo ^ 1;                    // MASK[i]: i even -> m=[0,1] (jm=1, jo=0)
    const float* w1 = m ? tW1 : sW1;  const float* b1 = m ? tB1 : sB1;
    const float* w3 = m ? tW3 : sW3;  const float* b2 = m ? tB2 : sB2;
    c1s[i][m][j] = w1[i * 128 + j * 2 + jm];
    b1s[i][m][j] = b1[i * 64 + j];
    wbs[i][m][j] = pkbf(b2[i * 64 + j], w3[i * 128 + jo * 64 + j]);
  }
  // ---- stage point state: z = error (base term recomputed in epilogue) ----
  #pragma unroll
  for (int it = 0; it < 2; ++it) {
    int idx = tid + it * BLOCK;
    int P = pbase + idx;
    float4 zs = make_float4(0.f, 0.f, 0.f, 0.f);
    if (P < M) {
      float4 p4 = ((const float4*)pred)[P];
      float2 t2 = ((const float2*)targ)[P];
      float s0 = sqrtf(fabsf(p4.z)), s1 = sqrtf(fabsf(p4.w));
      zs.x = (p4.x - t2.x) / (s0 + 1e-9f);
      zs.y = (p4.y - t2.y) / (s1 + 1e-9f);
    }
    zld[idx] = zs;
  }
  stage_layer(afr, sW2, tW2, 5, tid);   // first layer processed is i=5
  __syncthreads();

  const int wbase = wave * (T_TILES * 16);

  // ---- layer loop: i = 5..0 ----
  #pragma unroll 1
  for (int li = 0; li < 6; ++li) {
    const int i = 5 - li;
    const int jo = i & 1;             // component written this layer
    const bool upd0 = (jo == 0);      // jo==0: input comp is z1, output z0
    const float b3s = sB3[i * 2 + jo];
    const float b3t = tB3[i * 2 + jo];

    // ---- two passes: m=0 (s-net, store pre0), m=1 (t-net + coupling) ----
    #pragma unroll 1
    for (int m = 0; m < 2; ++m) {
      // === per-pass constants: loaded/unpacked ONCE, used by all 8 tiles ===
      u4_t af[8];                      // 32 regs: W2 A-frags
      #pragma unroll
      for (int f = 0; f < 8; ++f)
        af[f] = afr[(m * 8 + f) * 64 + lane];

      f4_t c1q[4], b1q[4];             // 32 regs: layer-1 coeffs for this lane's 16 k-slots
      #pragma unroll
      for (int q = 0; q < 2; ++q) {
        c1q[2 * q]     = *(const f4_t*)&c1s[i][m][q * 32 + 8 * g];
        c1q[2 * q + 1] = *(const f4_t*)&c1s[i][m][q * 32 + 8 * g + 4];
        b1q[2 * q]     = *(const f4_t*)&b1s[i][m][q * 32 + 8 * g];
        b1q[2 * q + 1] = *(const f4_t*)&b1s[i][m][q * 32 + 8 * g + 4];
      }
      f4_t b2u[4], w3u[4];             // 32 regs: unpacked ONCE per pass
      #pragma unroll
      for (int n = 0; n < 4; ++n) {
        u4_t wv = *(const u4_t*)&wbs[i][m][n * 16 + 4 * g];
        #pragma unroll
        for (int r = 0; r < 4; ++r) {
          b2u[n][r] = __uint_as_float(wv[r] << 16);
          w3u[n][r] = __uint_as_float(wv[r] & 0xffff0000u);
        }
      }

      // === tile loop: LDS traffic is state-only ===
      #pragma unroll 1
      for (int t = 0; t < T_TILES; ++t) {
        const int widx = wbase + t * 16 + pr;
        float4 zv = zld[widx];
        const float zin = upd0 ? zv.y : zv.x;     // masked-in component z[jm]

        f4_t acc[4];
        #pragma unroll
        for (int q = 0; q < 2; ++q) {
          const f4_t ca = c1q[2 * q], cb = c1q[2 * q + 1];
          const f4_t ba = b1q[2 * q], bb = b1q[2 * q + 1];
          float h0 = leaky(fmaf(ca[0], zin, ba[0]));
          float h1 = leaky(fmaf(ca[1], zin, ba[1]));
          float h2 = leaky(fmaf(ca[2], zin, ba[2]));
          float h3 = leaky(fmaf(ca[3], zin, ba[3]));
          float h4 = leaky(fmaf(cb[0], zin, bb[0]));
          float h5 = leaky(fmaf(cb[1], zin, bb[1]));
          float h6 = leaky(fmaf(cb[2], zin, bb[2]));
          float h7 = leaky(fmaf(cb[3], zin, bb[3]));
          bfrag_t B = __builtin_bit_cast(bfrag_t,
              make_uint4(pkbf(h0, h1), pkbf(h2, h3), pkbf(h4, h5), pkbf(h6, h7)));
          #pragma unroll
          for (int n = 0; n < 4; ++n) {
            f4_t c = (q == 0) ? b2u[n] : acc[n];   // b2 folded into first MFMA
            acc[n] = __builtin_amdgcn_mfma_f32_16x16x32_bf16(
                __builtin_bit_cast(bfrag_t, af[q * 4 + n]), B, c, 0, 0, 0);
          }
        }
        // layer 3: leaky(h2) . w3, then 4-group shuffle reduce
        float pa = 0.f;
        #pragma unroll
        for (int n = 0; n < 4; ++n)
          #pragma unroll
          for (int r = 0; r < 4; ++r)
            pa = fmaf(leaky(acc[n][r]), w3u[n][r], pa);
        pa += __shfl_xor(pa, 16);
        pa += __shfl_xor(pa, 32);

        if (m == 0) {
          if (g == 0) pre0v[widx] = pa;            // wave-private; no barrier
        } else {
          float p0  = pre0v[widx];
          float sv  = 1.f - 2.f / (__expf(2.f * (p0 + b3s)) + 1.f);   // tanh
          float tv  = pa + b3t;
          float zo  = upd0 ? zv.x : zv.y;
          float zn  = (zo - tv) * __expf(-sv);
          if (upd0) zv.x = zn; else zv.y = zn;
          zv.z -= sv;
          if (g == 0) zld[widx] = zv;
        }
      }
    }
    __syncthreads();
    if (li < 5) {
      stage_layer(afr, sW2, tW2, i - 1, tid);
      __syncthreads();
    }
  }

  // ---- epilogue: recompute base term from global, add prior + logdet, reduce ----
  float csum = 0.f;
  #pragma unroll
  for (int it = 0; it < 2; ++it) {
    int idx = tid + it * BLOCK;
    int P = pbase + idx;
    if (P < M) {
      float4 p4 = ((const float4*)pred)[P];
      float2 t2 = ((const float2*)targ)[P];
      float w   = twp[P];
      float s0 = sqrtf(fabsf(p4.z)), s1 = sqrtf(fabsf(p4.w));
      float e0 = (p4.x - t2.x) / (s0 + 1e-9f);
      float e1 = (p4.y - t2.y) / (s1 + 1e-9f);
      float bs = 2.f * (logf(s0) + logf(s1)) + TWO_LOG2 + fabsf(e0) + fabsf(e1);
      float4 zv = zld[idx];
      float prior = -0.5f * (zv.x * zv.x + zv.y * zv.y) - LOG_2PI;
      float lphi  = prior + zv.z;
      csum += (bs - 2.f * lphi) * w;
    }
  }
  #pragma unroll
  for (int off = 1; off <= 32; off <<= 1)
    csum += __shfl_xor(csum, off);
  if (lane == 0) wsum[wave] = csum;
  __syncthreads();
  if (tid == 0) {
    float tot = wsum[0] + wsum[1] + wsum[2] + wsum[3];
    atomicAdd(out, tot * (1.0f / 8192.0f));   // /pred.shape[0]
  }
}

extern "C" void kernel_launch(void* const* d_in, const int* in_sizes, int n_in,
                              void* d_out, int out_size, void* d_ws, size_t ws_size,
                              hipStream_t stream) {
  const float* pred = (const float*)d_in[0];
  const float* targ = (const float*)d_in[1];
  const float* twp  = (const float*)d_in[2];
  const float* sW1 = (const float*)d_in[3];  const float* sB1 = (const float*)d_in[4];
  const float* sW2 = (const float*)d_in[5];  const float* sB2 = (const float*)d_in[6];
  const float* sW3 = (const float*)d_in[7];  const float* sB3 = (const float*)d_in[8];
  const float* tW1 = (const float*)d_in[9];  const float* tB1 = (const float*)d_in[10];
  const float* tW2 = (const float*)d_in[11]; const float* tB2 = (const float*)d_in[12];
  const float* tW3 = (const float*)d_in[13]; const float* tB3 = (const float*)d_in[14];

  const int M = in_sizes[2];               // N*K points
  const int blocks = (M + PTS_BLK - 1) / PTS_BLK;

  hipMemsetAsync(d_out, 0, sizeof(float), stream);
  hipLaunchKernelGGL(ihll_kernel, dim3(blocks), dim3(BLOCK), 0, stream,
                     pred, targ, twp, sW1, sB1, sW2, sB2, sW3, sB3,
                     tW1, tB1, tW2, tB2, tW3, tB3, (float*)d_out, M);
}

// Round 10
// 231.977 us; speedup vs baseline: 6.1719x; 1.1721x over previous
//
#include <hip/hip_runtime.h>

typedef _Float16 hfrag_t __attribute__((ext_vector_type(8)));   // 8 x f16 (4 VGPRs)
typedef _Float16 h2_t    __attribute__((ext_vector_type(2)));
typedef __attribute__((ext_vector_type(4))) float    f4_t;
typedef __attribute__((ext_vector_type(4))) unsigned u4_t;

#define LOG_2PI   1.8378770664093453f
#define TWO_LOG2  1.3862943611198906f
#define T_TILES   8            // 16-point tiles per wave
#define BLOCK     256          // 4 waves
#define PTS_BLK   512          // 4 waves * 8 tiles * 16 pts
#define ZCLAMP    30000.0f     // keeps h1 = w1*z inside f16 range; only clips tanh-saturated pts

__device__ __forceinline__ unsigned pkh(float a, float b) {
  return __builtin_bit_cast(unsigned, __builtin_amdgcn_cvt_pkrtz(a, b));
}
__device__ __forceinline__ unsigned pk_fma_h(unsigned a, unsigned b, unsigned c) {
  unsigned d;
  asm("v_pk_fma_f16 %0, %1, %2, %3" : "=v"(d) : "v"(a), "v"(b), "v"(c));
  return d;
}
// packed leaky-relu: max(h, 0.01h) on 2 f16 lanes (2 insts)
__device__ __forceinline__ unsigned pk_leaky_h(unsigned h, unsigned k01) {
  unsigned t, r;
  asm("v_pk_mul_f16 %0, %1, %2" : "=v"(t) : "v"(h), "v"(k01));
  asm("v_pk_max_f16 %0, %1, %2" : "=v"(r) : "v"(h), "v"(t));
  return r;
}
__device__ __forceinline__ float dot2h(unsigned a, unsigned b, float c) {
  return __builtin_amdgcn_fdot2(__builtin_bit_cast(h2_t, a), __builtin_bit_cast(h2_t, b), c, false);
}

// Stage one layer's W2 (both MLPs) into LDS as f16 MFMA A-fragments.
// A-frag layout for mfma_f32_16x16x32_f16: lane l holds A[16n + (l&15)][32q + 8*(l>>4) + e], e=0..7
__device__ __forceinline__ void stage_layer(u4_t* afr, const float* sW2, const float* tW2,
                                            int layer, int tid) {
  #pragma unroll
  for (int it = 0; it < 4; ++it) {
    int idx = tid + it * BLOCK;          // 0..1023
    int l = idx & 63, f = (idx >> 6) & 7, m = (idx >> 9) & 1;
    int n = f & 3, q = f >> 2;
    int row = 16 * n + (l & 15), kb = 32 * q + 8 * (l >> 4);
    const float* src = (m ? tW2 : sW2) + layer * 4096 + row * 64 + kb;
    float4 a = *(const float4*)src;
    float4 b = *(const float4*)(src + 4);
    afr[(m * 8 + f) * 64 + l] =
        (u4_t){pkh(a.x, a.y), pkh(a.z, a.w), pkh(b.x, b.y), pkh(b.z, b.w)};
  }
}

__global__ __launch_bounds__(BLOCK)
void ihll_kernel(
    const float* __restrict__ pred, const float* __restrict__ targ, const float* __restrict__ twp,
    const float* __restrict__ sW1, const float* __restrict__ sB1, const float* __restrict__ sW2,
    const float* __restrict__ sB2, const float* __restrict__ sW3, const float* __restrict__ sB3,
    const float* __restrict__ tW1, const float* __restrict__ tB1, const float* __restrict__ tW2,
    const float* __restrict__ tB2, const float* __restrict__ tW3, const float* __restrict__ tB3,
    float* __restrict__ out, int M) {
  __shared__ u4_t     afr[2 * 8 * 64];     // 16KB f16 W2 A-frags
  __shared__ float4   zld[PTS_BLK];        // 8KB  (z0, z1, ldet, pad)
  __shared__ float    pre0v[PTS_BLK];      // 2KB  s-net preact (m=0 -> m=1, wave-private)
  __shared__ unsigned c1h[6][2][32];       // 1.5KB half2(w1[2jp],w1[2jp+1])
  __shared__ unsigned b1h[6][2][32];       // 1.5KB half2(b1)
  __shared__ unsigned w3h[6][2][4][8];     // 1.5KB [g][2n+j]: half2 of w3 rows 16n+4g+2j..+1
  __shared__ float    b2s[6][2][64];       // 3KB  b2 fp32 (MFMA C-init)
  __shared__ float    wsum[4];

  const int tid  = threadIdx.x;
  const int lane = tid & 63, wave = tid >> 6;
  const int pr   = lane & 15, g = lane >> 4;
  const int pbase = blockIdx.x * PTS_BLK;
  const unsigned k01h = pkh(0.01f, 0.01f);

  // ---- stage per-layer small tables (all 6 layers, once) ----
  for (int idx = tid; idx < 384; idx += BLOCK) {       // c1h/b1h: 6*2*32
    int i = idx >> 6, r = idx & 63, m = r >> 5, jp = r & 31;
    int jo = i & 1, jm = jo ^ 1;                       // MASK[i]: i even -> jm=1, jo=0
    const float* w1 = m ? tW1 : sW1;  const float* b1 = m ? tB1 : sB1;
    c1h[i][m][jp] = pkh(w1[i * 128 + 4 * jp + jm], w1[i * 128 + 4 * jp + 2 + jm]);
    b1h[i][m][jp] = pkh(b1[i * 64 + 2 * jp], b1[i * 64 + 2 * jp + 1]);
  }
  for (int idx = tid; idx < 384; idx += BLOCK) {       // w3h: 6*2*4*8
    int i = idx >> 6, r = idx & 63, m = r >> 5, c = r & 31;
    int gg = c >> 3, c2 = c & 7, n = c2 >> 1, jj = c2 & 1;
    int jo = i & 1;
    const float* w3 = m ? tW3 : sW3;
    int row = 16 * n + 4 * gg + 2 * jj;
    w3h[i][m][gg][c2] = pkh(w3[i * 128 + jo * 64 + row], w3[i * 128 + jo * 64 + row + 1]);
  }
  for (int idx = tid; idx < 768; idx += BLOCK) {       // b2s
    int i = idx >> 7, r = idx & 127, m = r >> 6, j = r & 63;
    const float* b2 = m ? tB2 : sB2;
    b2s[i][m][j] = b2[i * 64 + j];
  }
  // ---- stage point state: z = error (base term recomputed in epilogue) ----
  #pragma unroll
  for (int it = 0; it < 2; ++it) {
    int idx = tid + it * BLOCK;
    int P = pbase + idx;
    float4 zs = make_float4(0.f, 0.f, 0.f, 0.f);
    if (P < M) {
      float4 p4 = ((const float4*)pred)[P];
      float2 t2 = ((const float2*)targ)[P];
      float s0 = sqrtf(fabsf(p4.z)), s1 = sqrtf(fabsf(p4.w));
      zs.x = (p4.x - t2.x) / (s0 + 1e-9f);
      zs.y = (p4.y - t2.y) / (s1 + 1e-9f);
    }
    zld[idx] = zs;
  }
  stage_layer(afr, sW2, tW2, 5, tid);   // first layer processed is i=5
  __syncthreads();

  const int wbase = wave * (T_TILES * 16);
  const float* zldf = (const float*)zld;

  // ---- layer loop: i = 5..0 ----
  #pragma unroll 1
  for (int li = 0; li < 6; ++li) {
    const int i = 5 - li;
    const int jo = i & 1;             // component written this layer
    const bool upd0 = (jo == 0);      // jo==0: input comp is z1, output z0
    const float b3s = sB3[i * 2 + jo];
    const float b3t = tB3[i * 2 + jo];

    // ---- two specialized passes: m=0 (s-net), m=1 (t-net + coupling) ----
    #pragma unroll
    for (int m = 0; m < 2; ++m) {
      // === per-pass constants, loaded once (resident ~64 regs) ===
      u4_t af[8];
      #pragma unroll
      for (int f = 0; f < 8; ++f)
        af[f] = afr[(m * 8 + f) * 64 + lane];
      unsigned c1q[8], b1q[8];
      *(u4_t*)&c1q[0] = *(const u4_t*)&c1h[i][m][4 * g];        // q=0: jp=4g..
      *(u4_t*)&c1q[4] = *(const u4_t*)&c1h[i][m][16 + 4 * g];   // q=1
      *(u4_t*)&b1q[0] = *(const u4_t*)&b1h[i][m][4 * g];
      *(u4_t*)&b1q[4] = *(const u4_t*)&b1h[i][m][16 + 4 * g];
      unsigned w3q[8];
      *(u4_t*)&w3q[0] = *(const u4_t*)&w3h[i][m][g][0];          // n=0,1
      *(u4_t*)&w3q[4] = *(const u4_t*)&w3h[i][m][g][4];          // n=2,3
      f4_t b2q[4];
      #pragma unroll
      for (int n = 0; n < 4; ++n)
        b2q[n] = *(const f4_t*)&b2s[i][m][n * 16 + 4 * g];

      // === tile loop: LDS traffic is state-only ===
      #pragma unroll 1
      for (int t = 0; t < T_TILES; ++t) {
        const int widx = wbase + t * 16 + pr;
        float4 zv;
        float zin;
        if (m == 1) { zv = zld[widx]; zin = upd0 ? zv.y : zv.x; }
        else        { zin = zldf[4 * widx + (upd0 ? 1 : 0)]; }
        float zc = fmaxf(fminf(zin, ZCLAMP), -ZCLAMP);
        const unsigned zz = pkh(zc, zc);

        f4_t acc[4];
        #pragma unroll
        for (int q = 0; q < 2; ++q) {
          // layer 1: h1 = leaky(w1*z + b1) for this lane's 8 k-slots, packed f16
          unsigned hh[4];
          #pragma unroll
          for (int e = 0; e < 4; ++e)
            hh[e] = pk_leaky_h(pk_fma_h(c1q[q * 4 + e], zz, b1q[q * 4 + e]), k01h);
          hfrag_t B = __builtin_bit_cast(hfrag_t, (u4_t){hh[0], hh[1], hh[2], hh[3]});
          #pragma unroll
          for (int n = 0; n < 4; ++n) {
            f4_t c = (q == 0) ? b2q[n] : acc[n];   // b2 folded into first MFMA
            acc[n] = __builtin_amdgcn_mfma_f32_16x16x32_f16(
                __builtin_bit_cast(hfrag_t, af[q * 4 + n]), B, c, 0, 0, 0);
          }
        }
        // layer 3: leaky(h2) . w3 via packed f16 + v_dot2 (f32 accumulate)
        float pa = 0.f;
        #pragma unroll
        for (int n = 0; n < 4; ++n) {
          unsigned x01 = pk_leaky_h(pkh(acc[n][0], acc[n][1]), k01h);
          unsigned x23 = pk_leaky_h(pkh(acc[n][2], acc[n][3]), k01h);
          pa = dot2h(x01, w3q[2 * n], pa);
          pa = dot2h(x23, w3q[2 * n + 1], pa);
        }
        pa += __shfl_xor(pa, 16);
        pa += __shfl_xor(pa, 32);

        if (m == 0) {
          if (g == 0) pre0v[widx] = pa;            // wave-private; no barrier
        } else {
          float p0  = pre0v[widx];
          float sv  = 1.f - 2.f / (__expf(2.f * (p0 + b3s)) + 1.f);   // tanh
          float tv  = pa + b3t;
          float zo  = upd0 ? zv.x : zv.y;
          float zn  = (zo - tv) * __expf(-sv);
          if (upd0) zv.x = zn; else zv.y = zn;
          zv.z -= sv;
          if (g == 0) zld[widx] = zv;
        }
      }
    }
    __syncthreads();
    if (li < 5) {
      stage_layer(afr, sW2, tW2, i - 1, tid);
      __syncthreads();
    }
  }

  // ---- epilogue: recompute base term from global, add prior + logdet, reduce ----
  float csum = 0.f;
  #pragma unroll
  for (int it = 0; it < 2; ++it) {
    int idx = tid + it * BLOCK;
    int P = pbase + idx;
    if (P < M) {
      float4 p4 = ((const float4*)pred)[P];
      float2 t2 = ((const float2*)targ)[P];
      float w   = twp[P];
      float s0 = sqrtf(fabsf(p4.z)), s1 = sqrtf(fabsf(p4.w));
      float e0 = (p4.x - t2.x) / (s0 + 1e-9f);
      float e1 = (p4.y - t2.y) / (s1 + 1e-9f);
      float bs = 2.f * (logf(s0) + logf(s1)) + TWO_LOG2 + fabsf(e0) + fabsf(e1);
      float4 zv = zld[idx];
      float prior = -0.5f * (zv.x * zv.x + zv.y * zv.y) - LOG_2PI;
      float lphi  = prior + zv.z;
      csum += (bs - 2.f * lphi) * w;
    }
  }
  #pragma unroll
  for (int off = 1; off <= 32; off <<= 1)
    csum += __shfl_xor(csum, off);
  if (lane == 0) wsum[wave] = csum;
  __syncthreads();
  if (tid == 0) {
    float tot = wsum[0] + wsum[1] + wsum[2] + wsum[3];
    atomicAdd(out, tot * (1.0f / 8192.0f));   // /pred.shape[0]
  }
}

extern "C" void kernel_launch(void* const* d_in, const int* in_sizes, int n_in,
                              void* d_out, int out_size, void* d_ws, size_t ws_size,
                              hipStream_t stream) {
  const float* pred = (const float*)d_in[0];
  const float* targ = (const float*)d_in[1];
  const float* twp  = (const float*)d_in[2];
  const float* sW1 = (const float*)d_in[3];  const float* sB1 = (const float*)d_in[4];
  const float* sW2 = (const float*)d_in[5];  const float* sB2 = (const float*)d_in[6];
  const float* sW3 = (const float*)d_in[7];  const float* sB3 = (const float*)d_in[8];
  const float* tW1 = (const float*)d_in[9];  const float* tB1 = (const float*)d_in[10];
  const float* tW2 = (const float*)d_in[11]; const float* tB2 = (const float*)d_in[12];
  const float* tW3 = (const float*)d_in[13]; const float* tB3 = (const float*)d_in[14];

  const int M = in_sizes[2];               // N*K points
  const int blocks = (M + PTS_BLK - 1) / PTS_BLK;

  hipMemsetAsync(d_out, 0, sizeof(float), stream);
  hipLaunchKernelGGL(ihll_kernel, dim3(blocks), dim3(BLOCK), 0, stream,
                     pred, targ, twp, sW1, sB1, sW2, sB2, sW3, sB3,
                     tW1, tB1, tW2, tB2, tW3, tB3, (float*)d_out, M);
}

// Round 11
// 225.842 us; speedup vs baseline: 6.3396x; 1.0272x over previous
//
#include <hip/hip_runtime.h>

typedef _Float16 hfrag_t __attribute__((ext_vector_type(8)));   // 8 x f16 (4 VGPRs)
typedef _Float16 h2_t    __attribute__((ext_vector_type(2)));
typedef __attribute__((ext_vector_type(4))) float    f4_t;
typedef __attribute__((ext_vector_type(4))) unsigned u4_t;

#define LOG_2PI   1.8378770664093453f
#define TWO_LOG2  1.3862943611198906f
#define T_TILES   8            // 16-point tiles per wave
#define BLOCK     256          // 4 waves
#define PTS_BLK   512          // 4 waves * 8 tiles * 16 pts
#define ZCLAMP    30000.0f     // keeps h1 = w1*z inside f16 range; only clips tanh-saturated pts

__device__ __forceinline__ unsigned pkh(float a, float b) {
  return __builtin_bit_cast(unsigned, __builtin_amdgcn_cvt_pkrtz(a, b));
}
__device__ __forceinline__ unsigned pk_fma_h(unsigned a, unsigned b, unsigned c) {
  unsigned d;
  asm("v_pk_fma_f16 %0, %1, %2, %3" : "=v"(d) : "v"(a), "v"(b), "v"(c));
  return d;
}
// packed leaky-relu: max(h, 0.01h) on 2 f16 lanes (2 insts)
__device__ __forceinline__ unsigned pk_leaky_h(unsigned h, unsigned k01) {
  unsigned t, r;
  asm("v_pk_mul_f16 %0, %1, %2" : "=v"(t) : "v"(h), "v"(k01));
  asm("v_pk_max_f16 %0, %1, %2" : "=v"(r) : "v"(h), "v"(t));
  return r;
}
__device__ __forceinline__ float dot2h(unsigned a, unsigned b, float c) {
  return __builtin_amdgcn_fdot2(__builtin_bit_cast(h2_t, a), __builtin_bit_cast(h2_t, b), c, false);
}

// Stage one layer's W2 (both MLPs) into LDS as f16 MFMA A-fragments.
// A-frag layout for mfma_f32_16x16x32_f16: lane l holds A[16n + (l&15)][32q + 8*(l>>4) + e], e=0..7
__device__ __forceinline__ void stage_layer(u4_t* afr, const float* sW2, const float* tW2,
                                            int layer, int tid) {
  #pragma unroll
  for (int it = 0; it < 4; ++it) {
    int idx = tid + it * BLOCK;          // 0..1023
    int l = idx & 63, f = (idx >> 6) & 7, m = (idx >> 9) & 1;
    int n = f & 3, q = f >> 2;
    int row = 16 * n + (l & 15), kb = 32 * q + 8 * (l >> 4);
    const float* src = (m ? tW2 : sW2) + layer * 4096 + row * 64 + kb;
    float4 a = *(const float4*)src;
    float4 b = *(const float4*)(src + 4);
    afr[(m * 8 + f) * 64 + l] =
        (u4_t){pkh(a.x, a.y), pkh(a.z, a.w), pkh(b.x, b.y), pkh(b.z, b.w)};
  }
}

__global__ __launch_bounds__(BLOCK)
void ihll_kernel(
    const float* __restrict__ pred, const float* __restrict__ targ, const float* __restrict__ twp,
    const float* __restrict__ sW1, const float* __restrict__ sB1, const float* __restrict__ sW2,
    const float* __restrict__ sB2, const float* __restrict__ sW3, const float* __restrict__ sB3,
    const float* __restrict__ tW1, const float* __restrict__ tB1, const float* __restrict__ tW2,
    const float* __restrict__ tB2, const float* __restrict__ tW3, const float* __restrict__ tB3,
    float* __restrict__ out, int M) {
  __shared__ u4_t     afr[2 * 8 * 64];     // 16KB f16 W2 A-frags
  __shared__ float4   zld[PTS_BLK];        // 8KB  (z0, z1, ldet, pad)
  __shared__ float    pre0v[PTS_BLK];      // 2KB  s-net preact (m=0 -> m=1, wave-private)
  __shared__ unsigned c1h[6][2][32];       // 1.5KB half2(w1[2jp],w1[2jp+1])
  __shared__ unsigned b1h[6][2][32];       // 1.5KB half2(b1)
  __shared__ unsigned w3h[6][2][4][8];     // 1.5KB [g][2n+j]: half2 of w3 rows 16n+4g+2j..+1
  __shared__ float    b2s[6][2][64];       // 3KB  b2 fp32 (MFMA C-init)
  __shared__ float    wsum[4];

  const int tid  = threadIdx.x;
  const int lane = tid & 63, wave = tid >> 6;
  const int pr   = lane & 15, g = lane >> 4;
  const int pbase = blockIdx.x * PTS_BLK;
  const unsigned k01h = pkh(0.01f, 0.01f);

  // ---- stage per-layer small tables (all 6 layers, once) ----
  for (int idx = tid; idx < 384; idx += BLOCK) {       // c1h/b1h: 6*2*32
    int i = idx >> 6, r = idx & 63, m = r >> 5, jp = r & 31;
    int jo = i & 1, jm = jo ^ 1;                       // MASK[i]: i even -> jm=1, jo=0
    const float* w1 = m ? tW1 : sW1;  const float* b1 = m ? tB1 : sB1;
    c1h[i][m][jp] = pkh(w1[i * 128 + 4 * jp + jm], w1[i * 128 + 4 * jp + 2 + jm]);
    b1h[i][m][jp] = pkh(b1[i * 64 + 2 * jp], b1[i * 64 + 2 * jp + 1]);
  }
  for (int idx = tid; idx < 384; idx += BLOCK) {       // w3h: 6*2*4*8
    int i = idx >> 6, r = idx & 63, m = r >> 5, c = r & 31;
    int gg = c >> 3, c2 = c & 7, n = c2 >> 1, jj = c2 & 1;
    int jo = i & 1;
    const float* w3 = m ? tW3 : sW3;
    int row = 16 * n + 4 * gg + 2 * jj;
    w3h[i][m][gg][c2] = pkh(w3[i * 128 + jo * 64 + row], w3[i * 128 + jo * 64 + row + 1]);
  }
  for (int idx = tid; idx < 768; idx += BLOCK) {       // b2s
    int i = idx >> 7, r = idx & 127, m = r >> 6, j = r & 63;
    const float* b2 = m ? tB2 : sB2;
    b2s[i][m][j] = b2[i * 64 + j];
  }
  // ---- stage point state: z = error (base term recomputed in epilogue) ----
  #pragma unroll
  for (int it = 0; it < 2; ++it) {
    int idx = tid + it * BLOCK;
    int P = pbase + idx;
    float4 zs = make_float4(0.f, 0.f, 0.f, 0.f);
    if (P < M) {
      float4 p4 = ((const float4*)pred)[P];
      float2 t2 = ((const float2*)targ)[P];
      float s0 = sqrtf(fabsf(p4.z)), s1 = sqrtf(fabsf(p4.w));
      zs.x = (p4.x - t2.x) / (s0 + 1e-9f);
      zs.y = (p4.y - t2.y) / (s1 + 1e-9f);
    }
    zld[idx] = zs;
  }
  stage_layer(afr, sW2, tW2, 5, tid);   // first layer processed is i=5
  __syncthreads();

  const int wbase = wave * (T_TILES * 16);

  // ---- layer loop: i = 5..0 ----
  #pragma unroll 1
  for (int li = 0; li < 6; ++li) {
    const int i = 5 - li;
    const int jo = i & 1;             // component written this layer
    const bool upd0 = (jo == 0);      // jo==0: input comp is z1, output z0
    const float b3s = sB3[i * 2 + jo];
    const float b3t = tB3[i * 2 + jo];

    // ---- two passes: m=0 (s-net, store pre0), m=1 (t-net + coupling) ----
    #pragma unroll 1
    for (int m = 0; m < 2; ++m) {
      // per-pass constant tables (textually hoisted; compiler may re-read,
      // but the 2-tile pairing below amortizes whatever it re-issues)
      u4_t af[8];
      #pragma unroll
      for (int f = 0; f < 8; ++f)
        af[f] = afr[(m * 8 + f) * 64 + lane];
      unsigned c1q[8], b1q[8];
      *(u4_t*)&c1q[0] = *(const u4_t*)&c1h[i][m][4 * g];
      *(u4_t*)&c1q[4] = *(const u4_t*)&c1h[i][m][16 + 4 * g];
      *(u4_t*)&b1q[0] = *(const u4_t*)&b1h[i][m][4 * g];
      *(u4_t*)&b1q[4] = *(const u4_t*)&b1h[i][m][16 + 4 * g];
      unsigned w3q[8];
      *(u4_t*)&w3q[0] = *(const u4_t*)&w3h[i][m][g][0];
      *(u4_t*)&w3q[4] = *(const u4_t*)&w3h[i][m][g][4];
      f4_t b2q[4];
      #pragma unroll
      for (int n = 0; n < 4; ++n)
        b2q[n] = *(const f4_t*)&b2s[i][m][n * 16 + 4 * g];

      // === paired-tile loop: 2 independent chains/iter, constants shared ===
      #pragma unroll 1
      for (int tt = 0; tt < T_TILES / 2; ++tt) {
        const int wA = wbase + (2 * tt) * 16 + pr;
        const int wB = wA + 16;
        float4 zvA = zld[wA];
        float4 zvB = zld[wB];
        const float zinA = upd0 ? zvA.y : zvA.x;
        const float zinB = upd0 ? zvB.y : zvB.x;
        float zcA = fmaxf(fminf(zinA, ZCLAMP), -ZCLAMP);
        float zcB = fmaxf(fminf(zinB, ZCLAMP), -ZCLAMP);
        const unsigned zzA = pkh(zcA, zcA);
        const unsigned zzB = pkh(zcB, zcB);

        f4_t accA[4], accB[4];
        #pragma unroll
        for (int q = 0; q < 2; ++q) {
          unsigned hA[4], hB[4];
          #pragma unroll
          for (int e = 0; e < 4; ++e) {
            hA[e] = pk_leaky_h(pk_fma_h(c1q[q * 4 + e], zzA, b1q[q * 4 + e]), k01h);
            hB[e] = pk_leaky_h(pk_fma_h(c1q[q * 4 + e], zzB, b1q[q * 4 + e]), k01h);
          }
          hfrag_t BA = __builtin_bit_cast(hfrag_t, (u4_t){hA[0], hA[1], hA[2], hA[3]});
          hfrag_t BB = __builtin_bit_cast(hfrag_t, (u4_t){hB[0], hB[1], hB[2], hB[3]});
          #pragma unroll
          for (int n = 0; n < 4; ++n) {
            f4_t cA = (q == 0) ? b2q[n] : accA[n];   // b2 folded into first MFMA
            f4_t cB = (q == 0) ? b2q[n] : accB[n];
            accA[n] = __builtin_amdgcn_mfma_f32_16x16x32_f16(
                __builtin_bit_cast(hfrag_t, af[q * 4 + n]), BA, cA, 0, 0, 0);
            accB[n] = __builtin_amdgcn_mfma_f32_16x16x32_f16(
                __builtin_bit_cast(hfrag_t, af[q * 4 + n]), BB, cB, 0, 0, 0);
          }
        }
        // layer 3: leaky(h2) . w3 via packed f16 + v_dot2 (f32 accumulate)
        float pa = 0.f, pb = 0.f;
        #pragma unroll
        for (int n = 0; n < 4; ++n) {
          unsigned a01 = pk_leaky_h(pkh(accA[n][0], accA[n][1]), k01h);
          unsigned a23 = pk_leaky_h(pkh(accA[n][2], accA[n][3]), k01h);
          unsigned b01 = pk_leaky_h(pkh(accB[n][0], accB[n][1]), k01h);
          unsigned b23 = pk_leaky_h(pkh(accB[n][2], accB[n][3]), k01h);
          pa = dot2h(a01, w3q[2 * n], pa);
          pa = dot2h(a23, w3q[2 * n + 1], pa);
          pb = dot2h(b01, w3q[2 * n], pb);
          pb = dot2h(b23, w3q[2 * n + 1], pb);
        }
        pa += __shfl_xor(pa, 16);  pa += __shfl_xor(pa, 32);
        pb += __shfl_xor(pb, 16);  pb += __shfl_xor(pb, 32);

        if (m == 0) {
          if (g == 0) { pre0v[wA] = pa; pre0v[wB] = pb; }   // wave-private
        } else {
          float p0A = pre0v[wA], p0B = pre0v[wB];
          float svA = 1.f - 2.f / (__expf(2.f * (p0A + b3s)) + 1.f);   // tanh
          float svB = 1.f - 2.f / (__expf(2.f * (p0B + b3s)) + 1.f);
          float tvA = pa + b3t, tvB = pb + b3t;
          float zoA = upd0 ? zvA.x : zvA.y;
          float zoB = upd0 ? zvB.x : zvB.y;
          float znA = (zoA - tvA) * __expf(-svA);
          float znB = (zoB - tvB) * __expf(-svB);
          if (upd0) { zvA.x = znA; zvB.x = znB; } else { zvA.y = znA; zvB.y = znB; }
          zvA.z -= svA;  zvB.z -= svB;
          if (g == 0) { zld[wA] = zvA; zld[wB] = zvB; }
        }
      }
    }
    __syncthreads();
    if (li < 5) {
      stage_layer(afr, sW2, tW2, i - 1, tid);
      __syncthreads();
    }
  }

  // ---- epilogue: recompute base term from global, add prior + logdet, reduce ----
  float csum = 0.f;
  #pragma unroll
  for (int it = 0; it < 2; ++it) {
    int idx = tid + it * BLOCK;
    int P = pbase + idx;
    if (P < M) {
      float4 p4 = ((const float4*)pred)[P];
      float2 t2 = ((const float2*)targ)[P];
      float w   = twp[P];
      float s0 = sqrtf(fabsf(p4.z)), s1 = sqrtf(fabsf(p4.w));
      float e0 = (p4.x - t2.x) / (s0 + 1e-9f);
      float e1 = (p4.y - t2.y) / (s1 + 1e-9f);
      float bs = 2.f * (logf(s0) + logf(s1)) + TWO_LOG2 + fabsf(e0) + fabsf(e1);
      float4 zv = zld[idx];
      float prior = -0.5f * (zv.x * zv.x + zv.y * zv.y) - LOG_2PI;
      float lphi  = prior + zv.z;
      csum += (bs - 2.f * lphi) * w;
    }
  }
  #pragma unroll
  for (int off = 1; off <= 32; off <<= 1)
    csum += __shfl_xor(csum, off);
  if (lane == 0) wsum[wave] = csum;
  __syncthreads();
  if (tid == 0) {
    float tot = wsum[0] + wsum[1] + wsum[2] + wsum[3];
    atomicAdd(out, tot * (1.0f / 8192.0f));   // /pred.shape[0]
  }
}

extern "C" void kernel_launch(void* const* d_in, const int* in_sizes, int n_in,
                              void* d_out, int out_size, void* d_ws, size_t ws_size,
                              hipStream_t stream) {
  const float* pred = (const float*)d_in[0];
  const float* targ = (const float*)d_in[1];
  const float* twp  = (const float*)d_in[2];
  const float* sW1 = (const float*)d_in[3];  const float* sB1 = (const float*)d_in[4];
  const float* sW2 = (const float*)d_in[5];  const float* sB2 = (const float*)d_in[6];
  const float* sW3 = (const float*)d_in[7];  const float* sB3 = (const float*)d_in[8];
  const float* tW1 = (const float*)d_in[9];  const float* tB1 = (const float*)d_in[10];
  const float* tW2 = (const float*)d_in[11]; const float* tB2 = (const float*)d_in[12];
  const float* tW3 = (const float*)d_in[13]; const float* tB3 = (const float*)d_in[14];

  const int M = in_sizes[2];               // N*K points
  const int blocks = (M + PTS_BLK - 1) / PTS_BLK;

  hipMemsetAsync(d_out, 0, sizeof(float), stream);
  hipLaunchKernelGGL(ihll_kernel, dim3(blocks), dim3(BLOCK), 0, stream,
                     pred, targ, twp, sW1, sB1, sW2, sB2, sW3, sB3,
                     tW1, tB1, tW2, tB2, tW3, tB3, (float*)d_out, M);
}

// Round 12
// 225.050 us; speedup vs baseline: 6.3619x; 1.0035x over previous
//
#include <hip/hip_runtime.h>

typedef _Float16 hfrag_t __attribute__((ext_vector_type(8)));   // 8 x f16 (4 VGPRs)
typedef _Float16 h2_t    __attribute__((ext_vector_type(2)));
typedef __attribute__((ext_vector_type(4))) float    f4_t;
typedef __attribute__((ext_vector_type(4))) unsigned u4_t;

#define LOG_2PI   1.8378770664093453f
#define TWO_LOG2  1.3862943611198906f
#define T_TILES   8            // 16-point tiles per wave
#define BLOCK     256          // 4 waves
#define PTS_BLK   512          // 4 waves * 8 tiles * 16 pts
#define ZCLAMP    30000.0f     // keeps h1 = w1*z inside f16 range; only clips tanh-saturated pts

__device__ __forceinline__ unsigned pkh(float a, float b) {
  return __builtin_bit_cast(unsigned, __builtin_amdgcn_cvt_pkrtz(a, b));
}
__device__ __forceinline__ unsigned pk_fma_h(unsigned a, unsigned b, unsigned c) {
  unsigned d;
  asm("v_pk_fma_f16 %0, %1, %2, %3" : "=v"(d) : "v"(a), "v"(b), "v"(c));
  return d;
}
__device__ __forceinline__ unsigned pk_add_h(unsigned a, unsigned b) {
  unsigned d;
  asm("v_pk_add_f16 %0, %1, %2" : "=v"(d) : "v"(a), "v"(b));
  return d;
}
// packed leaky-relu: max(h, 0.01h) on 2 f16 lanes (2 insts)
__device__ __forceinline__ unsigned pk_leaky_h(unsigned h, unsigned k01) {
  unsigned t, r;
  asm("v_pk_mul_f16 %0, %1, %2" : "=v"(t) : "v"(h), "v"(k01));
  asm("v_pk_max_f16 %0, %1, %2" : "=v"(r) : "v"(h), "v"(t));
  return r;
}
__device__ __forceinline__ float dot2h(unsigned a, unsigned b, float c) {
  return __builtin_amdgcn_fdot2(__builtin_bit_cast(h2_t, a), __builtin_bit_cast(h2_t, b), c, false);
}

// Stage one layer's W2 (both MLPs) into LDS as f16 MFMA A-fragments.
// A-frag layout for mfma_f32_16x16x32_f16: lane l holds A[16n + (l&15)][32q + 8*(l>>4) + e], e=0..7
__device__ __forceinline__ void stage_layer(u4_t* afr, const float* sW2, const float* tW2,
                                            int layer, int tid) {
  #pragma unroll
  for (int it = 0; it < 4; ++it) {
    int idx = tid + it * BLOCK;          // 0..1023
    int l = idx & 63, f = (idx >> 6) & 7, m = (idx >> 9) & 1;
    int n = f & 3, q = f >> 2;
    int row = 16 * n + (l & 15), kb = 32 * q + 8 * (l >> 4);
    const float* src = (m ? tW2 : sW2) + layer * 4096 + row * 64 + kb;
    float4 a = *(const float4*)src;
    float4 b = *(const float4*)(src + 4);
    afr[(m * 8 + f) * 64 + l] =
        (u4_t){pkh(a.x, a.y), pkh(a.z, a.w), pkh(b.x, b.y), pkh(b.z, b.w)};
  }
}

__global__ __launch_bounds__(BLOCK)
__attribute__((amdgpu_waves_per_eu(2)))   // min-only: permit up to ~256 VGPR, no force
void ihll_kernel(
    const float* __restrict__ pred, const float* __restrict__ targ, const float* __restrict__ twp,
    const float* __restrict__ sW1, const float* __restrict__ sB1, const float* __restrict__ sW2,
    const float* __restrict__ sB2, const float* __restrict__ sW3, const float* __restrict__ sB3,
    const float* __restrict__ tW1, const float* __restrict__ tB1, const float* __restrict__ tW2,
    const float* __restrict__ tB2, const float* __restrict__ tW3, const float* __restrict__ tB3,
    float* __restrict__ out, int M) {
  __shared__ u4_t     afr[2 * 8 * 64];     // 16KB f16 W2 A-frags
  __shared__ float4   zld[PTS_BLK];        // 8KB  (z0, z1, ldet, pad)
  __shared__ float    pre0v[PTS_BLK];      // 2KB  s-net preact (m=0 -> m=1, wave-private)
  __shared__ unsigned c1h[6][2][32];       // 1.5KB half2(w1)
  __shared__ unsigned b1h[6][2][32];       // 1.5KB half2(b1)
  __shared__ unsigned w3h[6][2][4][8];     // 1.5KB [g][2n+j]: half2 of w3 rows 16n+4g+2j..+1
  __shared__ float    b2s[6][2][64];       // 3KB  b2 fp32 (MFMA C-init)
  __shared__ float    wsum[4];

  const int tid  = threadIdx.x;
  const int lane = tid & 63, wave = tid >> 6;
  const int pr   = lane & 15, g = lane >> 4;
  const int pbase = blockIdx.x * PTS_BLK;
  const unsigned k01h = pkh(0.01f, 0.01f);

  // ---- stage per-layer small tables (all 6 layers, once) ----
  for (int idx = tid; idx < 384; idx += BLOCK) {       // c1h/b1h
    int i = idx >> 6, r = idx & 63, m = r >> 5, jp = r & 31;
    int jo = i & 1, jm = jo ^ 1;                       // MASK[i]: i even -> jm=1, jo=0
    const float* w1 = m ? tW1 : sW1;  const float* b1 = m ? tB1 : sB1;
    c1h[i][m][jp] = pkh(w1[i * 128 + 4 * jp + jm], w1[i * 128 + 4 * jp + 2 + jm]);
    b1h[i][m][jp] = pkh(b1[i * 64 + 2 * jp], b1[i * 64 + 2 * jp + 1]);
  }
  for (int idx = tid; idx < 384; idx += BLOCK) {       // w3h
    int i = idx >> 6, r = idx & 63, m = r >> 5, c = r & 31;
    int gg = c >> 3, c2 = c & 7, n = c2 >> 1, jj = c2 & 1;
    int jo = i & 1;
    const float* w3 = m ? tW3 : sW3;
    int row = 16 * n + 4 * gg + 2 * jj;
    w3h[i][m][gg][c2] = pkh(w3[i * 128 + jo * 64 + row], w3[i * 128 + jo * 64 + row + 1]);
  }
  for (int idx = tid; idx < 768; idx += BLOCK) {       // b2s
    int i = idx >> 7, r = idx & 127, m = r >> 6, j = r & 63;
    const float* b2 = m ? tB2 : sB2;
    b2s[i][m][j] = b2[i * 64 + j];
  }
  // ---- stage point state: z = error (base term recomputed in epilogue) ----
  #pragma unroll
  for (int it = 0; it < 2; ++it) {
    int idx = tid + it * BLOCK;
    int P = pbase + idx;
    float4 zs = make_float4(0.f, 0.f, 0.f, 0.f);
    if (P < M) {
      float4 p4 = ((const float4*)pred)[P];
      float2 t2 = ((const float2*)targ)[P];
      float s0 = sqrtf(fabsf(p4.z)), s1 = sqrtf(fabsf(p4.w));
      zs.x = (p4.x - t2.x) / (s0 + 1e-9f);
      zs.y = (p4.y - t2.y) / (s1 + 1e-9f);
    }
    zld[idx] = zs;
  }
  stage_layer(afr, sW2, tW2, 5, tid);   // first layer processed is i=5
  __syncthreads();

  const int wbase = wave * (T_TILES * 16);

  // ---- layer loop: i = 5..0 ----
  #pragma unroll 1
  for (int li = 0; li < 6; ++li) {
    const int i = 5 - li;
    const int jo = i & 1;             // component written this layer
    const bool upd0 = (jo == 0);      // jo==0: input comp is z1, output z0
    const float b3s = sB3[i * 2 + jo];
    const float b3t = tB3[i * 2 + jo];

    // ---- two passes (compile-time m): m=0 s-net, m=1 t-net + coupling ----
    #pragma unroll
    for (int m = 0; m < 2; ++m) {
      u4_t af[8];
      #pragma unroll
      for (int f = 0; f < 8; ++f)
        af[f] = afr[(m * 8 + f) * 64 + lane];
      unsigned c1q[8], b1q[8];
      *(u4_t*)&c1q[0] = *(const u4_t*)&c1h[i][m][4 * g];
      *(u4_t*)&c1q[4] = *(const u4_t*)&c1h[i][m][16 + 4 * g];
      *(u4_t*)&b1q[0] = *(const u4_t*)&b1h[i][m][4 * g];
      *(u4_t*)&b1q[4] = *(const u4_t*)&b1h[i][m][16 + 4 * g];
      unsigned w3q[8];
      *(u4_t*)&w3q[0] = *(const u4_t*)&w3h[i][m][g][0];
      *(u4_t*)&w3q[4] = *(const u4_t*)&w3h[i][m][g][4];
      f4_t b2q[4];
      #pragma unroll
      for (int n = 0; n < 4; ++n)
        b2q[n] = *(const f4_t*)&b2s[i][m][n * 16 + 4 * g];

      // === 4-tile groups: 4 independent chains, constants shared ===
      #pragma unroll 1
      for (int tt = 0; tt < T_TILES / 4; ++tt) {
        const int w0 = wbase + (4 * tt) * 16 + pr;
        float4 zv0 = zld[w0];
        float4 zv1 = zld[w0 + 16];
        float4 zv2 = zld[w0 + 32];
        float4 zv3 = zld[w0 + 48];
        float zi0 = upd0 ? zv0.y : zv0.x;
        float zi1 = upd0 ? zv1.y : zv1.x;
        float zi2 = upd0 ? zv2.y : zv2.x;
        float zi3 = upd0 ? zv3.y : zv3.x;
        zi0 = fmaxf(fminf(zi0, ZCLAMP), -ZCLAMP);
        zi1 = fmaxf(fminf(zi1, ZCLAMP), -ZCLAMP);
        zi2 = fmaxf(fminf(zi2, ZCLAMP), -ZCLAMP);
        zi3 = fmaxf(fminf(zi3, ZCLAMP), -ZCLAMP);
        const unsigned zz0 = pkh(zi0, zi0), zz1 = pkh(zi1, zi1);
        const unsigned zz2 = pkh(zi2, zi2), zz3 = pkh(zi3, zi3);

        f4_t acc0[4], acc1[4], acc2[4], acc3[4];
        #pragma unroll
        for (int q = 0; q < 2; ++q) {
          unsigned h0[4], h1v[4], h2v[4], h3[4];
          #pragma unroll
          for (int e = 0; e < 4; ++e) {
            h0[e]  = pk_leaky_h(pk_fma_h(c1q[q * 4 + e], zz0, b1q[q * 4 + e]), k01h);
            h1v[e] = pk_leaky_h(pk_fma_h(c1q[q * 4 + e], zz1, b1q[q * 4 + e]), k01h);
            h2v[e] = pk_leaky_h(pk_fma_h(c1q[q * 4 + e], zz2, b1q[q * 4 + e]), k01h);
            h3[e]  = pk_leaky_h(pk_fma_h(c1q[q * 4 + e], zz3, b1q[q * 4 + e]), k01h);
          }
          hfrag_t B0 = __builtin_bit_cast(hfrag_t, (u4_t){h0[0], h0[1], h0[2], h0[3]});
          hfrag_t B1 = __builtin_bit_cast(hfrag_t, (u4_t){h1v[0], h1v[1], h1v[2], h1v[3]});
          hfrag_t B2 = __builtin_bit_cast(hfrag_t, (u4_t){h2v[0], h2v[1], h2v[2], h2v[3]});
          hfrag_t B3 = __builtin_bit_cast(hfrag_t, (u4_t){h3[0], h3[1], h3[2], h3[3]});
          #pragma unroll
          for (int n = 0; n < 4; ++n) {
            hfrag_t A = __builtin_bit_cast(hfrag_t, af[q * 4 + n]);
            acc0[n] = __builtin_amdgcn_mfma_f32_16x16x32_f16(A, B0, (q == 0) ? b2q[n] : acc0[n], 0, 0, 0);
            acc1[n] = __builtin_amdgcn_mfma_f32_16x16x32_f16(A, B1, (q == 0) ? b2q[n] : acc1[n], 0, 0, 0);
            acc2[n] = __builtin_amdgcn_mfma_f32_16x16x32_f16(A, B2, (q == 0) ? b2q[n] : acc2[n], 0, 0, 0);
            acc3[n] = __builtin_amdgcn_mfma_f32_16x16x32_f16(A, B3, (q == 0) ? b2q[n] : acc3[n], 0, 0, 0);
          }
        }
        // layer 3: leaky(h2).w3 with split (2-deep) dot chains per tile
        float p0a = 0.f, p0b = 0.f, p1a = 0.f, p1b = 0.f;
        float p2a = 0.f, p2b = 0.f, p3a = 0.f, p3b = 0.f;
        #pragma unroll
        for (int n = 0; n < 4; ++n) {
          unsigned a01 = pk_leaky_h(pkh(acc0[n][0], acc0[n][1]), k01h);
          unsigned a23 = pk_leaky_h(pkh(acc0[n][2], acc0[n][3]), k01h);
          unsigned b01 = pk_leaky_h(pkh(acc1[n][0], acc1[n][1]), k01h);
          unsigned b23 = pk_leaky_h(pkh(acc1[n][2], acc1[n][3]), k01h);
          unsigned c01 = pk_leaky_h(pkh(acc2[n][0], acc2[n][1]), k01h);
          unsigned c23 = pk_leaky_h(pkh(acc2[n][2], acc2[n][3]), k01h);
          unsigned d01 = pk_leaky_h(pkh(acc3[n][0], acc3[n][1]), k01h);
          unsigned d23 = pk_leaky_h(pkh(acc3[n][2], acc3[n][3]), k01h);
          if (n < 2) {
            p0a = dot2h(a01, w3q[2 * n], p0a);  p0a = dot2h(a23, w3q[2 * n + 1], p0a);
            p1a = dot2h(b01, w3q[2 * n], p1a);  p1a = dot2h(b23, w3q[2 * n + 1], p1a);
            p2a = dot2h(c01, w3q[2 * n], p2a);  p2a = dot2h(c23, w3q[2 * n + 1], p2a);
            p3a = dot2h(d01, w3q[2 * n], p3a);  p3a = dot2h(d23, w3q[2 * n + 1], p3a);
          } else {
            p0b = dot2h(a01, w3q[2 * n], p0b);  p0b = dot2h(a23, w3q[2 * n + 1], p0b);
            p1b = dot2h(b01, w3q[2 * n], p1b);  p1b = dot2h(b23, w3q[2 * n + 1], p1b);
            p2b = dot2h(c01, w3q[2 * n], p2b);  p2b = dot2h(c23, w3q[2 * n + 1], p2b);
            p3b = dot2h(d01, w3q[2 * n], p3b);  p3b = dot2h(d23, w3q[2 * n + 1], p3b);
          }
        }
        float pt0 = p0a + p0b, pt1 = p1a + p1b, pt2 = p2a + p2b, pt3 = p3a + p3b;

        if (m == 0) {
          // s-net: packed f16 reduce (tanh saturates -> f16-safe)
          unsigned r01 = pkh(pt0, pt1), r23 = pkh(pt2, pt3);
          r01 = pk_add_h(r01, __shfl_xor(r01, 16));
          r23 = pk_add_h(r23, __shfl_xor(r23, 16));
          r01 = pk_add_h(r01, __shfl_xor(r01, 32));
          r23 = pk_add_h(r23, __shfl_xor(r23, 32));
          if (g == 0) {
            h2_t v01 = __builtin_bit_cast(h2_t, r01);
            h2_t v23 = __builtin_bit_cast(h2_t, r23);
            pre0v[w0]      = (float)v01[0];
            pre0v[w0 + 16] = (float)v01[1];
            pre0v[w0 + 32] = (float)v23[0];
            pre0v[w0 + 48] = (float)v23[1];
          }
        } else {
          // t-net: scalar f32 reduce (range safety), then coupling update
          pt0 += __shfl_xor(pt0, 16);  pt0 += __shfl_xor(pt0, 32);
          pt1 += __shfl_xor(pt1, 16);  pt1 += __shfl_xor(pt1, 32);
          pt2 += __shfl_xor(pt2, 16);  pt2 += __shfl_xor(pt2, 32);
          pt3 += __shfl_xor(pt3, 16);  pt3 += __shfl_xor(pt3, 32);
          float s0v = 1.f - 2.f / (__expf(2.f * (pre0v[w0]      + b3s)) + 1.f);
          float s1v = 1.f - 2.f / (__expf(2.f * (pre0v[w0 + 16] + b3s)) + 1.f);
          float s2v = 1.f - 2.f / (__expf(2.f * (pre0v[w0 + 32] + b3s)) + 1.f);
          float s3v = 1.f - 2.f / (__expf(2.f * (pre0v[w0 + 48] + b3s)) + 1.f);
          float zo0 = upd0 ? zv0.x : zv0.y;
          float zo1 = upd0 ? zv1.x : zv1.y;
          float zo2 = upd0 ? zv2.x : zv2.y;
          float zo3 = upd0 ? zv3.x : zv3.y;
          float zn0 = (zo0 - (pt0 + b3t)) * __expf(-s0v);
          float zn1 = (zo1 - (pt1 + b3t)) * __expf(-s1v);
          float zn2 = (zo2 - (pt2 + b3t)) * __expf(-s2v);
          float zn3 = (zo3 - (pt3 + b3t)) * __expf(-s3v);
          if (upd0) { zv0.x = zn0; zv1.x = zn1; zv2.x = zn2; zv3.x = zn3; }
          else      { zv0.y = zn0; zv1.y = zn1; zv2.y = zn2; zv3.y = zn3; }
          zv0.z -= s0v;  zv1.z -= s1v;  zv2.z -= s2v;  zv3.z -= s3v;
          if (g == 0) {
            zld[w0]      = zv0;
            zld[w0 + 16] = zv1;
            zld[w0 + 32] = zv2;
            zld[w0 + 48] = zv3;
          }
        }
      }
    }
    __syncthreads();
    if (li < 5) {
      stage_layer(afr, sW2, tW2, i - 1, tid);
      __syncthreads();
    }
  }

  // ---- epilogue: recompute base term from global, add prior + logdet, reduce ----
  float csum = 0.f;
  #pragma unroll
  for (int it = 0; it < 2; ++it) {
    int idx = tid + it * BLOCK;
    int P = pbase + idx;
    if (P < M) {
      float4 p4 = ((const float4*)pred)[P];
      float2 t2 = ((const float2*)targ)[P];
      float w   = twp[P];
      float s0 = sqrtf(fabsf(p4.z)), s1 = sqrtf(fabsf(p4.w));
      float e0 = (p4.x - t2.x) / (s0 + 1e-9f);
      float e1 = (p4.y - t2.y) / (s1 + 1e-9f);
      float bs = 2.f * (logf(s0) + logf(s1)) + TWO_LOG2 + fabsf(e0) + fabsf(e1);
      float4 zv = zld[idx];
      float prior = -0.5f * (zv.x * zv.x + zv.y * zv.y) - LOG_2PI;
      float lphi  = prior + zv.z;
      csum += (bs - 2.f * lphi) * w;
    }
  }
  #pragma unroll
  for (int off = 1; off <= 32; off <<= 1)
    csum += __shfl_xor(csum, off);
  if (lane == 0) wsum[wave] = csum;
  __syncthreads();
  if (tid == 0) {
    float tot = wsum[0] + wsum[1] + wsum[2] + wsum[3];
    atomicAdd(out, tot * (1.0f / 8192.0f));   // /pred.shape[0]
  }
}

extern "C" void kernel_launch(void* const* d_in, const int* in_sizes, int n_in,
                              void* d_out, int out_size, void* d_ws, size_t ws_size,
                              hipStream_t stream) {
  const float* pred = (const float*)d_in[0];
  const float* targ = (const float*)d_in[1];
  const float* twp  = (const float*)d_in[2];
  const float* sW1 = (const float*)d_in[3];  const float* sB1 = (const float*)d_in[4];
  const float* sW2 = (const float*)d_in[5];  const float* sB2 = (const float*)d_in[6];
  const float* sW3 = (const float*)d_in[7];  const float* sB3 = (const float*)d_in[8];
  const float* tW1 = (const float*)d_in[9];  const float* tB1 = (const float*)d_in[10];
  const float* tW2 = (const float*)d_in[11]; const float* tB2 = (const float*)d_in[12];
  const float* tW3 = (const float*)d_in[13]; const float* tB3 = (const float*)d_in[14];

  const int M = in_sizes[2];               // N*K points
  const int blocks = (M + PTS_BLK - 1) / PTS_BLK;

  hipMemsetAsync(d_out, 0, sizeof(float), stream);
  hipLaunchKernelGGL(ihll_kernel, dim3(blocks), dim3(BLOCK), 0, stream,
                     pred, targ, twp, sW1, sB1, sW2, sB2, sW3, sB3,
                     tW1, tB1, tW2, tB2, tW3, tB3, (float*)d_out, M);
}